// Round 6
// baseline (457.537 us; speedup 1.0000x reference)
//
#include <hip/hip_runtime.h>
#include <math.h>

#define H 512
#define W 512
#define PLANE (H*W)       // 262144
#define PLANE4 (PLANE/4)  // 65536

typedef float v2f __attribute__((ext_vector_type(2)));
typedef unsigned int uint;
typedef unsigned short ushort;

__device__ __forceinline__ float bflo(uint u){ return __uint_as_float(u<<16); }
__device__ __forceinline__ float bfhi(uint u){ return __uint_as_float(u & 0xFFFF0000u); }
__device__ __forceinline__ uint bfpack(float f0, float f1){
  uint a = __float_as_uint(f0), b = __float_as_uint(f1);
  return ((a + 0x8000u) >> 16) | ((b + 0x8000u) & 0xFFFF0000u);
}
__device__ __forceinline__ ushort bf1(float f){
  return (ushort)((__float_as_uint(f) + 0x8000u) >> 16);
}
__device__ __forceinline__ v2f mkv2(float a, float b){ v2f r; r.x=a; r.y=b; return r; }

// packed 3x3 accumulate of one 4-wide-input-channel-group step over a 2x2 quad.
// pl: bf16 LDS plane (stride S ushorts), window rows YB..YB+3, cols XB..XB+3.
// ODD=false: XB even; ODD=true: XB odd (reads aligned u32 covering XB-1..XB+4).
// w: uniform weight base; co stride COS floats. acc0 = out row0 pair, acc1 = row1.
template<int S, int COS, bool ODD>
__device__ __forceinline__ void accp4(const ushort* __restrict__ pl,
    const float* __restrict__ w, int YB, int XB, v2f* acc0, v2f* acc1)
{
  v2f A[4], Mv[4], Bv[4];
  #pragma unroll
  for (int r=0;r<4;++r){
    const ushort* rp = pl + (YB+r)*S + XB;
    float q0,q1,q2,q3;
    if constexpr(!ODD){
      uint u0 = *(const uint*)rp;
      uint u1 = *(const uint*)(rp+2);
      q0=bflo(u0); q1=bfhi(u0); q2=bflo(u1); q3=bfhi(u1);
    } else {
      uint u0 = *(const uint*)(rp-1);
      uint u1 = *(const uint*)(rp+1);
      uint u2 = *(const uint*)(rp+3);
      q0=bfhi(u0); q1=bflo(u1); q2=bfhi(u1); q3=bflo(u2);
    }
    A[r]=mkv2(q0,q1); Mv[r]=mkv2(q1,q2); Bv[r]=mkv2(q2,q3);
  }
  #pragma unroll
  for (int dy=0; dy<3; ++dy){
    #pragma unroll
    for (int co=0; co<4; ++co){
      float w0=w[co*COS+dy*3+0], w1=w[co*COS+dy*3+1], w2=w[co*COS+dy*3+2];
      acc0[co] += A[dy]*w0;   acc0[co] += Mv[dy]*w1;   acc0[co] += Bv[dy]*w2;
      acc1[co] += A[dy+1]*w0; acc1[co] += Mv[dy+1]*w1; acc1[co] += Bv[dy+1]*w2;
    }
  }
}

// single-output-channel variant (c7), even XB only
template<int S>
__device__ __forceinline__ void accp1(const ushort* __restrict__ pl,
    const float* __restrict__ w, int YB, int XB, v2f& s0, v2f& s1)
{
  v2f A[4], Mv[4], Bv[4];
  #pragma unroll
  for (int r=0;r<4;++r){
    const ushort* rp = pl + (YB+r)*S + XB;
    uint u0 = *(const uint*)rp;
    uint u1 = *(const uint*)(rp+2);
    float q0=bflo(u0), q1=bfhi(u0), q2=bflo(u1), q3=bfhi(u1);
    A[r]=mkv2(q0,q1); Mv[r]=mkv2(q1,q2); Bv[r]=mkv2(q2,q3);
  }
  #pragma unroll
  for (int dy=0; dy<3; ++dy){
    float w0=w[dy*3+0], w1=w[dy*3+1], w2=w[dy*3+2];
    s0 += A[dy]*w0;   s0 += Mv[dy]*w1;   s0 += Bv[dy]*w2;
    s1 += A[dy+1]*w0; s1 += Mv[dy+1]*w1; s1 += Bv[dy+1]*w2;
  }
}

// ================= K1: v -> x1 -> x2 -> x3 (bf16) =================
__launch_bounds__(512,4)
__global__ void k_conv_a(const float* __restrict__ xg,
    const float* __restrict__ c1w, const float* __restrict__ c1b,
    const float* __restrict__ c2w, const float* __restrict__ c2b,
    const float* __restrict__ c3w, const float* __restrict__ c3b,
    ushort* __restrict__ x1p, ushort* __restrict__ x2p, ushort* __restrict__ x3p)
{
  __shared__ __align__(16) ushort vb[38*38];
  __shared__ __align__(16) ushort p1[4][36*36];
  __shared__ __align__(16) ushort p2[4][34*34];
  int wg=blockIdx.x, b=wg>>8, t=wg&255, ty=t>>4, tx=t&15;
  int gy0=ty*32, gx0=tx*32, tid=threadIdx.x;
  const float* xp = xg + (size_t)b*3*PLANE;

  // stage v window (origin gy0-3, gx0-3) as bf16 scalars
  for (int i=tid;i<38*38;i+=512){
    int rr=i/38, cc=i-rr*38;
    int gy=gy0-3+rr, gx=gx0-3+cc;
    float val=0.f;
    if (((unsigned)gy<512u)&((unsigned)gx<512u)){
      int off=gy*W+gx;
      val=(xp[off]+xp[PLANE+off]+xp[2*PLANE+off])*(1.f/3.f);
    }
    vb[i]=bf1(val);
  }
  __syncthreads();

  // c1: vb(38) -> p1(36) + x1 global, out origin (gy0-2, gx0-2)
  if (tid < 324){
    int qy=tid/18, qx=tid-qy*18, y0=2*qy, x0=2*qx;
    v2f acc0[4], acc1[4];
    #pragma unroll
    for (int co=0;co<4;++co){ float bv=c1b[co]; acc0[co]=mkv2(bv,bv); acc1[co]=acc0[co]; }
    accp4<38,9,false>(vb, c1w, y0, x0, acc0, acc1);
    bool okr0=(unsigned)(gy0-2+y0  )<512u;
    bool okr1=(unsigned)(gy0-2+y0+1)<512u;
    bool okc0=(unsigned)(gx0-2+x0  )<512u;
    bool okc1=(unsigned)(gx0-2+x0+1)<512u;
    bool ownc = (x0>=2) & (x0<33);
    bool ownr0 = (y0>=2) & (y0<34);
    bool ownr1 = (y0+1>=2) & (y0+1<34);
    #pragma unroll
    for (int co=0;co<4;++co){
      float v0=(okr0&okc0)?fmaxf(acc0[co].x,0.f):0.f;
      float v1=(okr0&okc1)?fmaxf(acc0[co].y,0.f):0.f;
      float v2=(okr1&okc0)?fmaxf(acc1[co].x,0.f):0.f;
      float v3=(okr1&okc1)?fmaxf(acc1[co].y,0.f):0.f;
      uint lo=bfpack(v0,v1), hi=bfpack(v2,v3);
      *(uint*)&p1[co][y0*36+x0]=lo;
      *(uint*)&p1[co][(y0+1)*36+x0]=hi;
      if (ownc){
        ushort* pl = x1p + ((size_t)(b*4+co))*PLANE;
        if (ownr0) *(uint*)&pl[(gy0-2+y0  )*512 + gx0-2+x0]=lo;
        if (ownr1) *(uint*)&pl[(gy0-2+y0+1)*512 + gx0-2+x0]=hi;
      }
    }
  }
  __syncthreads();

  // c2: p1(36) -> p2(34) + x2 global (short stores, odd cols), out origin (gy0-1, gx0-1)
  if (tid < 289){
    int qy=tid/17, qx=tid-qy*17, y0=2*qy, x0=2*qx;
    v2f acc0[4], acc1[4];
    #pragma unroll
    for (int co=0;co<4;++co){ float bv=c2b[co]; acc0[co]=mkv2(bv,bv); acc1[co]=acc0[co]; }
    #pragma unroll
    for (int ci=0;ci<4;++ci) accp4<36,36,false>(&p1[ci][0], c2w+ci*9, y0, x0, acc0, acc1);
    bool okr0=(unsigned)(gy0-1+y0  )<512u;
    bool okr1=(unsigned)(gy0-1+y0+1)<512u;
    bool okc0=(unsigned)(gx0-1+x0  )<512u;
    bool okc1=(unsigned)(gx0-1+x0+1)<512u;
    bool own0=(unsigned)(y0-1)<32u;
    bool own1=(unsigned)(y0)<32u;
    int gyA=gy0-1+y0, gxA=gx0-1+x0;
    #pragma unroll
    for (int co=0;co<4;++co){
      float v0=(okr0&okc0)?fmaxf(acc0[co].x,0.f):0.f;
      float v1=(okr0&okc1)?fmaxf(acc0[co].y,0.f):0.f;
      float v2=(okr1&okc0)?fmaxf(acc1[co].x,0.f):0.f;
      float v3=(okr1&okc1)?fmaxf(acc1[co].y,0.f):0.f;
      *(uint*)&p2[co][y0*34+x0]=bfpack(v0,v1);
      *(uint*)&p2[co][(y0+1)*34+x0]=bfpack(v2,v3);
      ushort* pl = x2p + ((size_t)(b*4+co))*PLANE;
      if (x0==0){
        if (own0) pl[gyA*512+gxA+1]=bf1(v1);
        if (own1) pl[(gyA+1)*512+gxA+1]=bf1(v3);
      } else if (x0==32){
        if (own0) pl[gyA*512+gxA]=bf1(v0);
        if (own1) pl[(gyA+1)*512+gxA]=bf1(v2);
      } else {
        if (own0){ pl[gyA*512+gxA]=bf1(v0); pl[gyA*512+gxA+1]=bf1(v1); }
        if (own1){ pl[(gyA+1)*512+gxA]=bf1(v2); pl[(gyA+1)*512+gxA+1]=bf1(v3); }
      }
    }
  }
  __syncthreads();

  // c3: p2(34) -> x3 global, out origin (gy0, gx0), interior
  if (tid < 256){
    int qy=tid>>4, qx=tid&15, y0=2*qy, x0=2*qx;
    v2f acc0[4], acc1[4];
    #pragma unroll
    for (int co=0;co<4;++co){ float bv=c3b[co]; acc0[co]=mkv2(bv,bv); acc1[co]=acc0[co]; }
    #pragma unroll
    for (int ci=0;ci<4;++ci) accp4<34,36,false>(&p2[ci][0], c3w+ci*9, y0, x0, acc0, acc1);
    #pragma unroll
    for (int co=0;co<4;++co){
      ushort* pl = x3p + ((size_t)(b*4+co))*PLANE;
      *(uint*)&pl[(gy0+y0  )*512 + gx0+x0]=bfpack(fmaxf(acc0[co].x,0.f),fmaxf(acc0[co].y,0.f));
      *(uint*)&pl[(gy0+y0+1)*512 + gx0+x0]=bfpack(fmaxf(acc1[co].x,0.f),fmaxf(acc1[co].y,0.f));
    }
  }
}

// ================= K2: x3 -> x4 -> x5 (bf16) =================
__launch_bounds__(512,4)
__global__ void k_conv_b(const ushort* __restrict__ x3p,
    const float* __restrict__ c4w, const float* __restrict__ c4b,
    const float* __restrict__ c5w, const float* __restrict__ c5b,
    ushort* __restrict__ x5p)
{
  __shared__ __align__(16) ushort p3[4][36*36];
  __shared__ __align__(16) ushort p4[4][34*34];
  int wg=blockIdx.x, b=wg>>8, t=wg&255, ty=t>>4, tx=t&15;
  int gy0=ty*32, gx0=tx*32, tid=threadIdx.x;

  // stage x3 window (origin gy0-2, gx0-2), uint granularity
  for (int i=tid; i<4*36*18; i+=512){
    int ch=i/648; int rem=i-ch*648;
    int rr=rem/18, cu=rem-rr*18;
    int gy=gy0-2+rr, base=gx0-2+2*cu;
    uint u=0;
    if (((unsigned)gy<512u)&((unsigned)base<=510u))
      u = *(const uint*)&x3p[((size_t)(b*4+ch))*PLANE + gy*512+base];
    *(uint*)&p3[ch][rr*36+2*cu]=u;
  }
  __syncthreads();

  // c4: p3(36) -> p4(34), out origin (gy0-1, gx0-1)
  if (tid < 289){
    int qy=tid/17, qx=tid-qy*17, y0=2*qy, x0=2*qx;
    v2f acc0[4], acc1[4];
    #pragma unroll
    for (int co=0;co<4;++co){ float bv=c4b[co]; acc0[co]=mkv2(bv,bv); acc1[co]=acc0[co]; }
    #pragma unroll
    for (int ci=0;ci<4;++ci) accp4<36,36,false>(&p3[ci][0], c4w+ci*9, y0, x0, acc0, acc1);
    bool okr0=(unsigned)(gy0-1+y0  )<512u;
    bool okr1=(unsigned)(gy0-1+y0+1)<512u;
    bool okc0=(unsigned)(gx0-1+x0  )<512u;
    bool okc1=(unsigned)(gx0-1+x0+1)<512u;
    #pragma unroll
    for (int co=0;co<4;++co){
      float v0=(okr0&okc0)?fmaxf(acc0[co].x,0.f):0.f;
      float v1=(okr0&okc1)?fmaxf(acc0[co].y,0.f):0.f;
      float v2=(okr1&okc0)?fmaxf(acc1[co].x,0.f):0.f;
      float v3=(okr1&okc1)?fmaxf(acc1[co].y,0.f):0.f;
      *(uint*)&p4[co][y0*34+x0]=bfpack(v0,v1);
      *(uint*)&p4[co][(y0+1)*34+x0]=bfpack(v2,v3);
    }
  }
  __syncthreads();

  // c5: concat(p3@(+1,+1) [ODD], p4) -> x5 global, out origin (gy0, gx0)
  if (tid < 256){
    int qy=tid>>4, qx=tid&15, y0=2*qy, x0=2*qx;
    v2f acc0[4], acc1[4];
    #pragma unroll
    for (int co=0;co<4;++co){ float bv=c5b[co]; acc0[co]=mkv2(bv,bv); acc1[co]=acc0[co]; }
    #pragma unroll
    for (int ci=0;ci<4;++ci) accp4<36,72,true >(&p3[ci][0], c5w+ci*9,     y0+1, x0+1, acc0, acc1);
    #pragma unroll
    for (int ci=0;ci<4;++ci) accp4<34,72,false>(&p4[ci][0], c5w+(4+ci)*9, y0,   x0,   acc0, acc1);
    #pragma unroll
    for (int co=0;co<4;++co){
      ushort* pl = x5p + ((size_t)(b*4+co))*PLANE;
      *(uint*)&pl[(gy0+y0  )*512 + gx0+x0]=bfpack(fmaxf(acc0[co].x,0.f),fmaxf(acc0[co].y,0.f));
      *(uint*)&pl[(gy0+y0+1)*512 + gx0+x0]=bfpack(fmaxf(acc1[co].x,0.f),fmaxf(acc1[co].y,0.f));
    }
  }
}

// ================= K3: x2,x5 -> x6 ; x1,x6 -> v_r =================
__launch_bounds__(512,4)
__global__ void k_conv_c(const ushort* __restrict__ x1p,
    const ushort* __restrict__ x2p, const ushort* __restrict__ x5p,
    const float* __restrict__ c6w, const float* __restrict__ c6b,
    const float* __restrict__ c7w, const float* __restrict__ c7b,
    float* __restrict__ vr)
{
  __shared__ __align__(16) ushort p2s[4][36*36];
  __shared__ __align__(16) ushort p5[4][36*36];
  __shared__ __align__(16) ushort p1s[4][34*34];
  __shared__ __align__(16) ushort p6[4][34*34];
  int wg=blockIdx.x, b=wg>>8, t=wg&255, ty=t>>4, tx=t&15;
  int gy0=ty*32, gx0=tx*32, tid=threadIdx.x;

  // stage x2, x5 (origin gy0-2, gx0-2), uint granularity
  for (int i=tid; i<2*4*36*18; i+=512){
    int pi=i/2592; int rem0=i-pi*2592;
    int ch=rem0/648; int rem=rem0-ch*648;
    int rr=rem/18, cu=rem-rr*18;
    int gy=gy0-2+rr, base=gx0-2+2*cu;
    uint u=0;
    const ushort* sp = (pi==0 ? x2p : x5p) + ((size_t)(b*4+ch))*PLANE;
    if (((unsigned)gy<512u)&((unsigned)base<=510u))
      u = *(const uint*)&sp[gy*512+base];
    if (pi==0) *(uint*)&p2s[ch][rr*36+2*cu]=u;
    else       *(uint*)&p5 [ch][rr*36+2*cu]=u;
  }
  // stage x1 (origin gy0-1, gx0-1): odd global start -> shift-combine two aligned uints
  for (int i=tid; i<4*34*17; i+=512){
    int ch=i/578; int rem=i-ch*578;
    int rr=rem/17, cu=rem-rr*17;
    int gy=gy0-1+rr;
    int b0=gx0-2+2*cu, b1=gx0+2*cu;
    uint u0=0, u1=0;
    const ushort* sp = x1p + ((size_t)(b*4+ch))*PLANE;
    if ((unsigned)gy<512u){
      if ((unsigned)b0<=510u) u0 = *(const uint*)&sp[gy*512+b0];
      if ((unsigned)b1<=510u) u1 = *(const uint*)&sp[gy*512+b1];
    }
    *(uint*)&p1s[ch][rr*34+2*cu] = (u0>>16)|(u1<<16);
  }
  __syncthreads();

  // c6: concat(p2s, p5) -> p6(34), out origin (gy0-1, gx0-1)
  if (tid < 289){
    int qy=tid/17, qx=tid-qy*17, y0=2*qy, x0=2*qx;
    v2f acc0[4], acc1[4];
    #pragma unroll
    for (int co=0;co<4;++co){ float bv=c6b[co]; acc0[co]=mkv2(bv,bv); acc1[co]=acc0[co]; }
    #pragma unroll
    for (int ci=0;ci<4;++ci) accp4<36,72,false>(&p2s[ci][0], c6w+ci*9,     y0, x0, acc0, acc1);
    #pragma unroll
    for (int ci=0;ci<4;++ci) accp4<36,72,false>(&p5[ci][0],  c6w+(4+ci)*9, y0, x0, acc0, acc1);
    bool okr0=(unsigned)(gy0-1+y0  )<512u;
    bool okr1=(unsigned)(gy0-1+y0+1)<512u;
    bool okc0=(unsigned)(gx0-1+x0  )<512u;
    bool okc1=(unsigned)(gx0-1+x0+1)<512u;
    #pragma unroll
    for (int co=0;co<4;++co){
      float v0=(okr0&okc0)?fmaxf(acc0[co].x,0.f):0.f;
      float v1=(okr0&okc1)?fmaxf(acc0[co].y,0.f):0.f;
      float v2=(okr1&okc0)?fmaxf(acc1[co].x,0.f):0.f;
      float v3=(okr1&okc1)?fmaxf(acc1[co].y,0.f):0.f;
      *(uint*)&p6[co][y0*34+x0]=bfpack(v0,v1);
      *(uint*)&p6[co][(y0+1)*34+x0]=bfpack(v2,v3);
    }
  }
  __syncthreads();

  // c7: concat(p1s, p6) -> sigmoid -> v_r, out origin (gy0, gx0)
  if (tid < 256){
    int qy=tid>>4, qx=tid&15, y0=2*qy, x0=2*qx;
    float bv=c7b[0];
    v2f s0=mkv2(bv,bv), s1=s0;
    #pragma unroll
    for (int ci=0;ci<4;++ci) accp1<34>(&p1s[ci][0], c7w+ci*9,     y0, x0, s0, s1);
    #pragma unroll
    for (int ci=0;ci<4;++ci) accp1<34>(&p6[ci][0],  c7w+(4+ci)*9, y0, x0, s0, s1);
    float* vo = vr + (size_t)b*PLANE;
    *(float2*)&vo[(gy0+y0  )*512 + gx0+x0] =
        make_float2(1.f/(1.f+expf(-s0.x)), 1.f/(1.f+expf(-s0.y)));
    *(float2*)&vo[(gy0+y0+1)*512 + gx0+x0] =
        make_float2(1.f/(1.f+expf(-s1.x)), 1.f/(1.f+expf(-s1.y)));
  }
}

// ---------------- subsample + m-conv(stride2) + leaky + instance norm -> src(S,B,E) ----------------
__launch_bounds__(256)
__global__ void k_mnorm(const float* __restrict__ xg, const float* __restrict__ mw,
                        const float* __restrict__ mb, const float* __restrict__ ing,
                        const float* __restrict__ inb, float* __restrict__ src){
  int bc = blockIdx.x;           // 128 = b*16+c
  int b = bc >> 4, c = bc & 15;
  int tid = threadIdx.x;         // 256 = out pixel (i*16+j)
  int i = tid >> 4, j = tid & 15;
  const float* xp = xg + (size_t)b*3*PLANE;
  float s = mb[c];
  #pragma unroll
  for (int dy=0; dy<3; ++dy){
    int ii = 2*i - 1 + dy;
    if ((unsigned)ii >= 32u) continue;
    #pragma unroll
    for (int dx=0; dx<3; ++dx){
      int jj = 2*j - 1 + dx;
      if ((unsigned)jj >= 32u) continue;
      int off = (ii*16)*W + jj*16;
      float vv = (xp[off] + xp[PLANE+off] + xp[2*PLANE+off]) * (1.f/3.f);
      s += vv * mw[c*9 + dy*3 + dx];
    }
  }
  float h = (s >= 0.f) ? s : 0.2f*s;
  __shared__ float red[256];
  red[tid] = h; __syncthreads();
  for (int off=128; off; off>>=1){ if (tid<off) red[tid]+=red[tid+off]; __syncthreads(); }
  float mu = red[0] * (1.f/256.f);
  __syncthreads();
  float d = h - mu;
  red[tid] = d*d; __syncthreads();
  for (int off=128; off; off>>=1){ if (tid<off) red[tid]+=red[tid+off]; __syncthreads(); }
  float var = red[0] * (1.f/256.f);
  float yv = d * rsqrtf(var + 1e-5f) * ing[c] + inb[c];
  src[(size_t)tid*128 + b*16 + c] = yv;   // src[s][b][e], s=tid
}

// ---------------- qkv projection ----------------
__launch_bounds__(256)
__global__ void k_qkv(const float* __restrict__ src, const float* __restrict__ aw,
                      const float* __restrict__ ab, float* __restrict__ qkv){
  int id = blockIdx.x*256 + threadIdx.x;  // 2048*48 = 98304
  int tok = id / 48, o = id % 48;
  const float* sr = src + tok*16;
  float s = ab[o];
  #pragma unroll
  for (int e=0; e<16; ++e) s += sr[e]*aw[o*16+e];
  qkv[tok*48+o] = s;
}

// ---------------- attention (per b,h block; head dim = 2) ----------------
__launch_bounds__(256)
__global__ void k_attn(const float* __restrict__ qkv, float* __restrict__ obuf){
  int b = blockIdx.x >> 3, hh = blockIdx.x & 7;  // 64 blocks
  int t = threadIdx.x;                           // s index
  __shared__ float kk0[256], kk1[256], vv0[256], vv1[256];
  int tok = t*8 + b;
  const float* qr = qkv + tok*48;
  kk0[t] = qr[16 + hh*2]; kk1[t] = qr[16 + hh*2 + 1];
  vv0[t] = qr[32 + hh*2]; vv1[t] = qr[32 + hh*2 + 1];
  float q0 = qr[hh*2], q1 = qr[hh*2 + 1];
  __syncthreads();
  const float sc = 0.70710678118654752f;  // 1/sqrt(2)
  float m = -1e30f;
  for (int u=0; u<256; ++u){
    float s = (q0*kk0[u] + q1*kk1[u]) * sc;
    m = fmaxf(m, s);
  }
  float l = 0.f, a0 = 0.f, a1 = 0.f;
  for (int u=0; u<256; ++u){
    float s = (q0*kk0[u] + q1*kk1[u]) * sc;
    float p = expf(s - m);
    l += p; a0 += p*vv0[u]; a1 += p*vv1[u];
  }
  float inv = 1.f/l;
  obuf[tok*16 + hh*2]     = a0*inv;
  obuf[tok*16 + hh*2 + 1] = a1*inv;
}

// ---------------- out-proj + residual + layernorm1 (in-place on src) ----------------
__launch_bounds__(256)
__global__ void k_oproj_ln(const float* __restrict__ obuf, const float* __restrict__ ow,
                           const float* __restrict__ obias, const float* __restrict__ g,
                           const float* __restrict__ bb, float* __restrict__ src){
  int tok = blockIdx.x*256 + threadIdx.x;  // 2048
  const float* orow = obuf + tok*16;
  float xv[16];
  #pragma unroll
  for (int e=0; e<16; ++e){
    float s = obias[e];
    #pragma unroll
    for (int f=0; f<16; ++f) s += orow[f]*ow[e*16+f];
    xv[e] = src[tok*16+e] + s;
  }
  float mu = 0.f;
  #pragma unroll
  for (int e=0; e<16; ++e) mu += xv[e];
  mu *= (1.f/16.f);
  float var = 0.f;
  #pragma unroll
  for (int e=0; e<16; ++e){ float d = xv[e]-mu; var += d*d; }
  var *= (1.f/16.f);
  float rs = rsqrtf(var + 1e-5f);
  #pragma unroll
  for (int e=0; e<16; ++e) src[tok*16+e] = (xv[e]-mu)*rs*g[e] + bb[e];
}

// ---------------- FFN + residual + layernorm2 (in-place on src) ----------------
__launch_bounds__(64)
__global__ void k_ffn_ln(float* __restrict__ src, const float* __restrict__ w1,
                         const float* __restrict__ b1, const float* __restrict__ w2,
                         const float* __restrict__ b2, const float* __restrict__ g,
                         const float* __restrict__ bb){
  int tok = blockIdx.x;     // 2048
  int tid = threadIdx.x;    // 64
  __shared__ float srow[16], h1[128], xr[16];
  if (tid < 16) srow[tid] = src[tok*16+tid];
  __syncthreads();
  for (int i = tid; i < 128; i += 64){
    float s = b1[i];
    #pragma unroll
    for (int e=0; e<16; ++e) s += srow[e]*w1[i*16+e];
    h1[i] = fmaxf(s, 0.f);
  }
  __syncthreads();
  if (tid < 16){
    float s = b2[tid];
    for (int j=0; j<128; ++j) s += h1[j]*w2[tid*128+j];
    xr[tid] = srow[tid] + s;
  }
  __syncthreads();
  if (tid < 16){
    float mu = 0.f;
    #pragma unroll
    for (int e=0; e<16; ++e) mu += xr[e];
    mu *= (1.f/16.f);
    float var = 0.f;
    #pragma unroll
    for (int e=0; e<16; ++e){ float d = xr[e]-mu; var += d*d; }
    var *= (1.f/16.f);
    src[tok*16+tid] = (xr[tid]-mu)*rsqrtf(var+1e-5f)*g[tid] + bb[tid];
  }
}

// ---------------- final 16x16 valid conv -> level -> g/bcf scalars ----------------
__launch_bounds__(256)
__global__ void k_level(const float* __restrict__ src, const float* __restrict__ fw,
                        const float* __restrict__ fb, float* __restrict__ gb){
  int b = blockIdx.x >> 1, k = blockIdx.x & 1;  // 16 blocks
  int tid = threadIdx.x;                        // s pixel
  float s = 0.f;
  #pragma unroll
  for (int c=0; c<16; ++c)
    s += src[(size_t)tid*128 + b*16 + c] * fw[(k*16+c)*256 + tid];
  __shared__ float red[256];
  red[tid] = s; __syncthreads();
  for (int off=128; off; off>>=1){ if (tid<off) red[tid]+=red[tid+off]; __syncthreads(); }
  if (tid == 0){
    float lev = 1.f/(1.f + expf(-(red[0] + fb[k])));
    gb[b*2+k] = (k==0) ? (0.1f*lev + 0.2f) : (0.04f*lev + 0.06f);
  }
}

// ---------------- final elementwise: enhance + t ----------------
__launch_bounds__(256)
__global__ void k_final(const float* __restrict__ x, const float* __restrict__ gb,
                        float* __restrict__ out){
  int id = blockIdx.x*256 + threadIdx.x;  // 524288
  int b = id >> 16, p = id & 65535;
  const float4* xr = (const float4*)(x + (size_t)(b*3+0)*PLANE);
  const float4* xg = (const float4*)(x + (size_t)(b*3+1)*PLANE);
  const float4* xb = (const float4*)(x + (size_t)(b*3+2)*PLANE);
  const float4* vrp = (const float4*)(out + 6291456 + (size_t)b*PLANE);
  float4 R = xr[p], G = xg[p], Bl = xb[p], VR = vrp[p];
  float gg = gb[b*2+0], bc = gb[b*2+1];
  float lg = log2f(gg);
  float4 er, eg, eb, tr, tg, tb;
#define COMP(SUF, RF, GF, BF, VRF) {            \
    float vv = (RF + GF + BF)/3.f;              \
    float v0 = fminf(fmaxf(vv, 1e-6f), 0.999999f); \
    float r0 = exp2f(VRF * lg);                 \
    float ev0 = exp2f(r0 * log2f(v0));          \
    float d = bc - vv;                          \
    float L = 400.f*d*d*d;                      \
    L = (L < 1e-5f) ? 1e-6f : L;                \
    float fac = (ev0 - L) / (vv + 1e-6f);       \
    er.SUF = RF*fac; eg.SUF = GF*fac; eb.SUF = BF*fac; \
    bool z = vv > 0.04f;                        \
    tr.SUF = z ? 0.f : er.SUF; tg.SUF = z ? 0.f : eg.SUF; tb.SUF = z ? 0.f : eb.SUF; }
  COMP(x, R.x, G.x, Bl.x, VR.x)
  COMP(y, R.y, G.y, Bl.y, VR.y)
  COMP(z, R.z, G.z, Bl.z, VR.z)
  COMP(w, R.w, G.w, Bl.w, VR.w)
#undef COMP
  float4* oe = (float4*)out;
  float4* ot = (float4*)(out + 8388608);
  oe[(size_t)(b*3+0)*PLANE4 + p] = er;
  oe[(size_t)(b*3+1)*PLANE4 + p] = eg;
  oe[(size_t)(b*3+2)*PLANE4 + p] = eb;
  ot[(size_t)(b*3+0)*PLANE4 + p] = tr;
  ot[(size_t)(b*3+1)*PLANE4 + p] = tg;
  ot[(size_t)(b*3+2)*PLANE4 + p] = tb;
}

extern "C" void kernel_launch(void* const* d_in, const int* in_sizes, int n_in,
                              void* d_out, int out_size, void* d_ws, size_t ws_size,
                              hipStream_t stream) {
  const float* x    = (const float*)d_in[0];
  const float* c1w  = (const float*)d_in[1];  const float* c1b = (const float*)d_in[2];
  const float* c2w  = (const float*)d_in[3];  const float* c2b = (const float*)d_in[4];
  const float* c3w  = (const float*)d_in[5];  const float* c3b = (const float*)d_in[6];
  const float* c4w  = (const float*)d_in[7];  const float* c4b = (const float*)d_in[8];
  const float* c5w  = (const float*)d_in[9];  const float* c5b = (const float*)d_in[10];
  const float* c6w  = (const float*)d_in[11]; const float* c6b = (const float*)d_in[12];
  const float* c7w  = (const float*)d_in[13]; const float* c7b = (const float*)d_in[14];
  const float* mw   = (const float*)d_in[15]; const float* mb  = (const float*)d_in[16];
  const float* ing  = (const float*)d_in[17]; const float* inb = (const float*)d_in[18];
  const float* aw   = (const float*)d_in[19]; const float* ab  = (const float*)d_in[20];
  const float* ow   = (const float*)d_in[21]; const float* ob  = (const float*)d_in[22];
  const float* l1w  = (const float*)d_in[23]; const float* l1b = (const float*)d_in[24];
  const float* l2w  = (const float*)d_in[25]; const float* l2b = (const float*)d_in[26];
  const float* n1g  = (const float*)d_in[27]; const float* n1b = (const float*)d_in[28];
  const float* n2g  = (const float*)d_in[29]; const float* n2b = (const float*)d_in[30];
  const float* fw   = (const float*)d_in[31]; const float* fb  = (const float*)d_in[32];

  ushort* wsu = (ushort*)d_ws;
  ushort* x1p = wsu;                   // each 8*4*PLANE ushorts = 16.8 MB
  ushort* x2p = x1p + (size_t)8*4*PLANE;
  ushort* x3p = x2p + (size_t)8*4*PLANE;
  ushort* x5p = x3p + (size_t)8*4*PLANE;
  float* smallws = (float*)(x5p + (size_t)8*4*PLANE);
  float* src  = smallws;               // 32,768
  float* qkv  = src + 32768;           // 98,304
  float* obuf = qkv + 98304;           // 32,768
  float* gb   = obuf+ 32768;           // 16
  float* out  = (float*)d_out;
  float* vr   = out + 6291456;         // v_r output region

  k_conv_a<<<2048,512,0,stream>>>(x, c1w,c1b, c2w,c2b, c3w,c3b, x1p, x2p, x3p);
  k_conv_b<<<2048,512,0,stream>>>(x3p, c4w,c4b, c5w,c5b, x5p);
  k_conv_c<<<2048,512,0,stream>>>(x1p, x2p, x5p, c6w,c6b, c7w,c7b, vr);
  k_mnorm<<<128,256,0,stream>>>(x, mw, mb, ing, inb, src);
  k_qkv<<<384,256,0,stream>>>(src, aw, ab, qkv);
  k_attn<<<64,256,0,stream>>>(qkv, obuf);
  k_oproj_ln<<<8,256,0,stream>>>(obuf, ow, ob, n1g, n1b, src);
  k_ffn_ln<<<2048,64,0,stream>>>(src, l1w, l1b, l2w, l2b, n2g, n2b);
  k_level<<<16,256,0,stream>>>(src, fw, fb, gb);
  k_final<<<2048,256,0,stream>>>(x, gb, out);
}

// Round 7
// 419.629 us; speedup vs baseline: 1.0903x; 1.0903x over previous
//
#include <hip/hip_runtime.h>
#include <math.h>

#define H 512
#define W 512
#define PLANE (H*W)       // 262144
#define PLANE4 (PLANE/4)  // 65536

typedef float v2f __attribute__((ext_vector_type(2)));
typedef unsigned int uint;
typedef unsigned short ushort;

// NHWC bf16 plane: idx = ((b*512+y)*512+x)*4 + c
#define PIDX(B,Y,X) (((((size_t)(B)*512)+(Y))*512+(X))*4)

__device__ __forceinline__ float bflo(uint u){ return __uint_as_float(u<<16); }
__device__ __forceinline__ float bfhi(uint u){ return __uint_as_float(u & 0xFFFF0000u); }
__device__ __forceinline__ uint bfpack(float f0, float f1){
  uint a = __float_as_uint(f0), b = __float_as_uint(f1);
  return ((a + 0x8000u) >> 16) | ((b + 0x8000u) & 0xFFFF0000u);
}
__device__ __forceinline__ v2f mkv2(float a, float b){ v2f r; r.x=a; r.y=b; return r; }

// ---- unpack one NHWC row window of 4 pixels (XB even) into P[pixel][ch] ----
#define UNPACK_ROW(P, TL, S, ROWIDX, XB) { \
  uint4 U0 = *(const uint4*)&(TL)[(((ROWIDX))*(S)+(XB))*4]; \
  uint4 U1 = *(const uint4*)&(TL)[(((ROWIDX))*(S)+(XB)+2)*4]; \
  P[0][0]=bflo(U0.x); P[0][1]=bfhi(U0.x); P[0][2]=bflo(U0.y); P[0][3]=bfhi(U0.y); \
  P[1][0]=bflo(U0.z); P[1][1]=bfhi(U0.z); P[1][2]=bflo(U0.w); P[1][3]=bfhi(U0.w); \
  P[2][0]=bflo(U1.x); P[2][1]=bfhi(U1.x); P[2][2]=bflo(U1.y); P[2][3]=bfhi(U1.y); \
  P[3][0]=bflo(U1.z); P[3][1]=bfhi(U1.z); P[3][2]=bflo(U1.w); P[3][3]=bfhi(U1.w); }

// XB odd: pixels XB..XB+3 via three aligned uint4 (XB-1 even)
#define UNPACK_ROW_ODD(P, TL, S, ROWIDX, XB) { \
  uint4 U0 = *(const uint4*)&(TL)[(((ROWIDX))*(S)+(XB)-1)*4]; \
  uint4 U1 = *(const uint4*)&(TL)[(((ROWIDX))*(S)+(XB)+1)*4]; \
  uint4 U2 = *(const uint4*)&(TL)[(((ROWIDX))*(S)+(XB)+3)*4]; \
  P[0][0]=bflo(U0.z); P[0][1]=bfhi(U0.z); P[0][2]=bflo(U0.w); P[0][3]=bfhi(U0.w); \
  P[1][0]=bflo(U1.x); P[1][1]=bfhi(U1.x); P[1][2]=bflo(U1.y); P[1][3]=bfhi(U1.y); \
  P[2][0]=bflo(U1.z); P[2][1]=bfhi(U1.z); P[2][2]=bflo(U1.w); P[2][3]=bfhi(U1.w); \
  P[3][0]=bflo(U2.x); P[3][1]=bfhi(U2.x); P[3][2]=bflo(U2.y); P[3][3]=bfhi(U2.y); }

// one dy slice, 4 ci x 4 co, packed pairs. RL=top rows, RH=bottom rows.
#define DY4(RL, RH, Wb, INC, CIB, DYI) { \
  _Pragma("unroll") \
  for (int ci=0;ci<4;++ci){ \
    v2f A0=mkv2(RL[0][ci],RL[1][ci]), M0=mkv2(RL[1][ci],RL[2][ci]), B0=mkv2(RL[2][ci],RL[3][ci]); \
    v2f A1=mkv2(RH[0][ci],RH[1][ci]), M1=mkv2(RH[1][ci],RH[2][ci]), B1=mkv2(RH[2][ci],RH[3][ci]); \
    _Pragma("unroll") \
    for (int co=0;co<4;++co){ \
      const float* wp = (Wb) + ((co*(INC))+(CIB)+ci)*9 + (DYI)*3; \
      float w0=wp[0], w1=wp[1], w2=wp[2]; \
      acc0[co]+=A0*w0; acc0[co]+=M0*w1; acc0[co]+=B0*w2; \
      acc1[co]+=A1*w0; acc1[co]+=M1*w1; acc1[co]+=B1*w2; \
    } } }

#define ACC4_NHWC(TL, S, Wb, INC, CIB, YB, XB, ODDF) { \
  float r0_[4][4], r1_[4][4], r2_[4][4], r3_[4][4]; \
  if (ODDF){ UNPACK_ROW_ODD(r0_,TL,S,(YB)+0,XB) UNPACK_ROW_ODD(r1_,TL,S,(YB)+1,XB) } \
  else     { UNPACK_ROW(r0_,TL,S,(YB)+0,XB)     UNPACK_ROW(r1_,TL,S,(YB)+1,XB) } \
  DY4(r0_, r1_, Wb, INC, CIB, 0) \
  if (ODDF){ UNPACK_ROW_ODD(r2_,TL,S,(YB)+2,XB) } else { UNPACK_ROW(r2_,TL,S,(YB)+2,XB) } \
  DY4(r1_, r2_, Wb, INC, CIB, 1) \
  if (ODDF){ UNPACK_ROW_ODD(r3_,TL,S,(YB)+3,XB) } else { UNPACK_ROW(r3_,TL,S,(YB)+3,XB) } \
  DY4(r2_, r3_, Wb, INC, CIB, 2) }

// single-output-channel (c7)
#define DY1(RL, RH, Wb, CIB, DYI) { \
  _Pragma("unroll") \
  for (int ci=0;ci<4;++ci){ \
    v2f A0=mkv2(RL[0][ci],RL[1][ci]), M0=mkv2(RL[1][ci],RL[2][ci]), B0=mkv2(RL[2][ci],RL[3][ci]); \
    v2f A1=mkv2(RH[0][ci],RH[1][ci]), M1=mkv2(RH[1][ci],RH[2][ci]), B1=mkv2(RH[2][ci],RH[3][ci]); \
    const float* wp=(Wb)+((CIB)+ci)*9+(DYI)*3; \
    float w0=wp[0],w1=wp[1],w2=wp[2]; \
    s0+=A0*w0; s0+=M0*w1; s0+=B0*w2; \
    s1+=A1*w0; s1+=M1*w1; s1+=B1*w2; } }

#define ACC1_NHWC(TL, S, Wb, CIB, YB, XB) { \
  float r0_[4][4], r1_[4][4], r2_[4][4], r3_[4][4]; \
  UNPACK_ROW(r0_,TL,S,(YB)+0,XB) UNPACK_ROW(r1_,TL,S,(YB)+1,XB) \
  DY1(r0_,r1_,Wb,CIB,0) \
  UNPACK_ROW(r2_,TL,S,(YB)+2,XB) \
  DY1(r1_,r2_,Wb,CIB,1) \
  UNPACK_ROW(r3_,TL,S,(YB)+3,XB) \
  DY1(r2_,r3_,Wb,CIB,2) }

// scalar-plane (v) -> 4 co (c1); XB even, stride S ushorts
template<int S>
__device__ __forceinline__ void accp4sc(const ushort* __restrict__ pl,
    const float* __restrict__ w, int YB, int XB, v2f* acc0, v2f* acc1)
{
  v2f A[4], Mv[4], Bv[4];
  #pragma unroll
  for (int r=0;r<4;++r){
    const ushort* rp = pl + (YB+r)*S + XB;
    uint u0 = *(const uint*)rp;
    uint u1 = *(const uint*)(rp+2);
    float q0=bflo(u0), q1=bfhi(u0), q2=bflo(u1), q3=bfhi(u1);
    A[r]=mkv2(q0,q1); Mv[r]=mkv2(q1,q2); Bv[r]=mkv2(q2,q3);
  }
  #pragma unroll
  for (int dy=0; dy<3; ++dy){
    #pragma unroll
    for (int co=0; co<4; ++co){
      float w0=w[co*9+dy*3+0], w1=w[co*9+dy*3+1], w2=w[co*9+dy*3+2];
      acc0[co] += A[dy]*w0;   acc0[co] += Mv[dy]*w1;   acc0[co] += Bv[dy]*w2;
      acc1[co] += A[dy+1]*w0; acc1[co] += Mv[dy+1]*w1; acc1[co] += Bv[dy+1]*w2;
    }
  }
}

// pack quad accumulators (masked relu) into two NHWC row uint4s
#define PACK_ROWS(RL4, RH4, M00, M01, M10, M11) \
  uint4 RL4, RH4; { \
    float v00[4],v01[4],v10[4],v11[4]; \
    _Pragma("unroll") \
    for (int co=0;co<4;++co){ \
      v00[co]=(M00)?fmaxf(acc0[co].x,0.f):0.f; \
      v01[co]=(M01)?fmaxf(acc0[co].y,0.f):0.f; \
      v10[co]=(M10)?fmaxf(acc1[co].x,0.f):0.f; \
      v11[co]=(M11)?fmaxf(acc1[co].y,0.f):0.f; } \
    RL4.x=bfpack(v00[0],v00[1]); RL4.y=bfpack(v00[2],v00[3]); \
    RL4.z=bfpack(v01[0],v01[1]); RL4.w=bfpack(v01[2],v01[3]); \
    RH4.x=bfpack(v10[0],v10[1]); RH4.y=bfpack(v10[2],v10[3]); \
    RH4.z=bfpack(v11[0],v11[1]); RH4.w=bfpack(v11[2],v11[3]); }

// ================= K1: v -> x1 -> x2 -> x3 (bf16 NHWC) =================
__launch_bounds__(512,4)
__global__ void k_conv_a(const float* __restrict__ xg,
    const float* __restrict__ c1w, const float* __restrict__ c1b,
    const float* __restrict__ c2w, const float* __restrict__ c2b,
    const float* __restrict__ c3w, const float* __restrict__ c3b,
    ushort* __restrict__ x1p, ushort* __restrict__ x2p, ushort* __restrict__ x3p)
{
  __shared__ __align__(16) ushort vb[38*38];
  __shared__ __align__(16) ushort p1[36*36*4];
  __shared__ __align__(16) ushort p2[34*34*4];
  int wg=blockIdx.x, b=wg>>8, t=wg&255, ty=t>>4, tx=t&15;
  int gy0=ty*32, gx0=tx*32, tid=threadIdx.x;
  const float* xp = xg + (size_t)b*3*PLANE;

  for (int i=tid;i<38*38;i+=512){
    int rr=i/38, cc=i-rr*38;
    int gy=gy0-3+rr, gx=gx0-3+cc;
    float val=0.f;
    if (((unsigned)gy<512u)&((unsigned)gx<512u)){
      int off=gy*W+gx;
      val=(xp[off]+xp[PLANE+off]+xp[2*PLANE+off])*(1.f/3.f);
    }
    vb[i]=(ushort)((__float_as_uint(val)+0x8000u)>>16);
  }
  __syncthreads();

  // c1: vb(38) -> p1(36 NHWC) + x1 global, out origin (gy0-2, gx0-2)
  if (tid < 324){
    int qy=tid/18, qx=tid-qy*18, y0=2*qy, x0=2*qx;
    v2f acc0[4], acc1[4];
    #pragma unroll
    for (int co=0;co<4;++co){ float bv=c1b[co]; acc0[co]=mkv2(bv,bv); acc1[co]=acc0[co]; }
    accp4sc<38>(vb, c1w, y0, x0, acc0, acc1);
    bool okr0=(unsigned)(gy0-2+y0  )<512u;
    bool okr1=(unsigned)(gy0-2+y0+1)<512u;
    bool okc0=(unsigned)(gx0-2+x0  )<512u;
    bool okc1=(unsigned)(gx0-2+x0+1)<512u;
    PACK_ROWS(rowlo, rowhi, okr0&okc0, okr0&okc1, okr1&okc0, okr1&okc1)
    *(uint4*)&p1[(y0*36+x0)*4]=rowlo;
    *(uint4*)&p1[((y0+1)*36+x0)*4]=rowhi;
    if ((x0>=2)&(x0<33)){
      if ((y0>=2)&(y0<34))   *(uint4*)&x1p[PIDX(b, gy0-2+y0,   gx0-2+x0)]=rowlo;
      if ((y0+1>=2)&(y0+1<34)) *(uint4*)&x1p[PIDX(b, gy0-2+y0+1, gx0-2+x0)]=rowhi;
    }
  }
  __syncthreads();

  // c2: p1(36) -> p2(34) + x2 global, out origin (gy0-1, gx0-1)
  if (tid < 289){
    int qy=tid/17, qx=tid-qy*17, y0=2*qy, x0=2*qx;
    v2f acc0[4], acc1[4];
    #pragma unroll
    for (int co=0;co<4;++co){ float bv=c2b[co]; acc0[co]=mkv2(bv,bv); acc1[co]=acc0[co]; }
    ACC4_NHWC(p1, 36, c2w, 4, 0, y0, x0, false)
    bool okr0=(unsigned)(gy0-1+y0  )<512u;
    bool okr1=(unsigned)(gy0-1+y0+1)<512u;
    bool okc0=(unsigned)(gx0-1+x0  )<512u;
    bool okc1=(unsigned)(gx0-1+x0+1)<512u;
    PACK_ROWS(rowlo, rowhi, okr0&okc0, okr0&okc1, okr1&okc0, okr1&okc1)
    *(uint4*)&p2[(y0*34+x0)*4]=rowlo;
    *(uint4*)&p2[((y0+1)*34+x0)*4]=rowhi;
    bool own0=(unsigned)(y0-1)<32u;
    bool own1=(unsigned)(y0)<32u;
    int gyA=gy0-1+y0, gxA=gx0-1+x0;
    uint2 px00=make_uint2(rowlo.x,rowlo.y), px01=make_uint2(rowlo.z,rowlo.w);
    uint2 px10=make_uint2(rowhi.x,rowhi.y), px11=make_uint2(rowhi.z,rowhi.w);
    if (x0==0){
      if (own0) *(uint2*)&x2p[PIDX(b,gyA,  gxA+1)]=px01;
      if (own1) *(uint2*)&x2p[PIDX(b,gyA+1,gxA+1)]=px11;
    } else if (x0==32){
      if (own0) *(uint2*)&x2p[PIDX(b,gyA,  gxA)]=px00;
      if (own1) *(uint2*)&x2p[PIDX(b,gyA+1,gxA)]=px10;
    } else {
      if (own0){ *(uint2*)&x2p[PIDX(b,gyA,  gxA)]=px00; *(uint2*)&x2p[PIDX(b,gyA,  gxA+1)]=px01; }
      if (own1){ *(uint2*)&x2p[PIDX(b,gyA+1,gxA)]=px10; *(uint2*)&x2p[PIDX(b,gyA+1,gxA+1)]=px11; }
    }
  }
  __syncthreads();

  // c3: p2(34) -> x3 global, out origin (gy0, gx0), interior
  if (tid < 256){
    int qy=tid>>4, qx=tid&15, y0=2*qy, x0=2*qx;
    v2f acc0[4], acc1[4];
    #pragma unroll
    for (int co=0;co<4;++co){ float bv=c3b[co]; acc0[co]=mkv2(bv,bv); acc1[co]=acc0[co]; }
    ACC4_NHWC(p2, 34, c3w, 4, 0, y0, x0, false)
    PACK_ROWS(rowlo, rowhi, true, true, true, true)
    *(uint4*)&x3p[PIDX(b, gy0+y0,   gx0+x0)]=rowlo;
    *(uint4*)&x3p[PIDX(b, gy0+y0+1, gx0+x0)]=rowhi;
  }
}

// ================= K2: x3 -> x4 -> x5 (bf16 NHWC) =================
__launch_bounds__(512,4)
__global__ void k_conv_b(const ushort* __restrict__ x3p,
    const float* __restrict__ c4w, const float* __restrict__ c4b,
    const float* __restrict__ c5w, const float* __restrict__ c5b,
    ushort* __restrict__ x5p)
{
  __shared__ __align__(16) ushort p3[36*36*4];
  __shared__ __align__(16) ushort p4[34*34*4];
  int wg=blockIdx.x, b=wg>>8, t=wg&255, ty=t>>4, tx=t&15;
  int gy0=ty*32, gx0=tx*32, tid=threadIdx.x;

  // stage x3 window (origin gy0-2, gx0-2): 36 rows x 18 uint4 (2 px each)
  for (int i=tid; i<648; i+=512){
    int rr=i/18, cu=i-rr*18;
    int gy=gy0-2+rr, gx=gx0-2+2*cu;
    uint4 u=make_uint4(0,0,0,0);
    if (((unsigned)gy<512u)&((unsigned)gx<=510u))
      u = *(const uint4*)&x3p[PIDX(b,gy,gx)];
    *(uint4*)&p3[(rr*36+2*cu)*4]=u;
  }
  __syncthreads();

  // c4: p3(36) -> p4(34), out origin (gy0-1, gx0-1)
  if (tid < 289){
    int qy=tid/17, qx=tid-qy*17, y0=2*qy, x0=2*qx;
    v2f acc0[4], acc1[4];
    #pragma unroll
    for (int co=0;co<4;++co){ float bv=c4b[co]; acc0[co]=mkv2(bv,bv); acc1[co]=acc0[co]; }
    ACC4_NHWC(p3, 36, c4w, 4, 0, y0, x0, false)
    bool okr0=(unsigned)(gy0-1+y0  )<512u;
    bool okr1=(unsigned)(gy0-1+y0+1)<512u;
    bool okc0=(unsigned)(gx0-1+x0  )<512u;
    bool okc1=(unsigned)(gx0-1+x0+1)<512u;
    PACK_ROWS(rowlo, rowhi, okr0&okc0, okr0&okc1, okr1&okc0, okr1&okc1)
    *(uint4*)&p4[(y0*34+x0)*4]=rowlo;
    *(uint4*)&p4[((y0+1)*34+x0)*4]=rowhi;
  }
  __syncthreads();

  // c5: concat(p3 shifted (+1,+1) [odd], p4) -> x5, out origin (gy0, gx0)
  if (tid < 256){
    int qy=tid>>4, qx=tid&15, y0=2*qy, x0=2*qx;
    v2f acc0[4], acc1[4];
    #pragma unroll
    for (int co=0;co<4;++co){ float bv=c5b[co]; acc0[co]=mkv2(bv,bv); acc1[co]=acc0[co]; }
    ACC4_NHWC(p3, 36, c5w, 8, 0, y0+1, x0+1, true)
    ACC4_NHWC(p4, 34, c5w, 8, 4, y0,   x0,   false)
    PACK_ROWS(rowlo, rowhi, true, true, true, true)
    *(uint4*)&x5p[PIDX(b, gy0+y0,   gx0+x0)]=rowlo;
    *(uint4*)&x5p[PIDX(b, gy0+y0+1, gx0+x0)]=rowhi;
  }
}

// ================= K3: x2,x5 -> x6 ; x1,x6 -> v_r =================
__launch_bounds__(512,4)
__global__ void k_conv_c(const ushort* __restrict__ x1p,
    const ushort* __restrict__ x2p, const ushort* __restrict__ x5p,
    const float* __restrict__ c6w, const float* __restrict__ c6b,
    const float* __restrict__ c7w, const float* __restrict__ c7b,
    float* __restrict__ vr)
{
  __shared__ __align__(16) ushort p2s[36*36*4];
  __shared__ __align__(16) ushort p5 [36*36*4];
  __shared__ __align__(16) ushort p1s[34*34*4];
  __shared__ __align__(16) ushort p6 [34*34*4];
  int wg=blockIdx.x, b=wg>>8, t=wg&255, ty=t>>4, tx=t&15;
  int gy0=ty*32, gx0=tx*32, tid=threadIdx.x;

  // stage x2 and x5 windows (origin gy0-2, gx0-2): 2 x 36 rows x 18 uint4
  for (int i=tid; i<1296; i+=512){
    int pi=i/648; int rem=i-pi*648;
    int rr=rem/18, cu=rem-rr*18;
    int gy=gy0-2+rr, gx=gx0-2+2*cu;
    uint4 u=make_uint4(0,0,0,0);
    const ushort* sp = pi==0 ? x2p : x5p;
    if (((unsigned)gy<512u)&((unsigned)gx<=510u))
      u = *(const uint4*)&sp[PIDX(b,gy,gx)];
    if (pi==0) *(uint4*)&p2s[(rr*36+2*cu)*4]=u;
    else       *(uint4*)&p5 [(rr*36+2*cu)*4]=u;
  }
  // stage x1 window (origin gy0-1, gx0-1): 34 rows x 34 px, uint2 each
  for (int i=tid; i<1156; i+=512){
    int rr=i/34, px=i-rr*34;
    int gy=gy0-1+rr, gx=gx0-1+px;
    uint2 u=make_uint2(0,0);
    if (((unsigned)gy<512u)&((unsigned)gx<512u))
      u = *(const uint2*)&x1p[PIDX(b,gy,gx)];
    *(uint2*)&p1s[(rr*34+px)*4]=u;
  }
  __syncthreads();

  // c6: concat(p2s, p5) -> p6(34), out origin (gy0-1, gx0-1)
  if (tid < 289){
    int qy=tid/17, qx=tid-qy*17, y0=2*qy, x0=2*qx;
    v2f acc0[4], acc1[4];
    #pragma unroll
    for (int co=0;co<4;++co){ float bv=c6b[co]; acc0[co]=mkv2(bv,bv); acc1[co]=acc0[co]; }
    ACC4_NHWC(p2s, 36, c6w, 8, 0, y0, x0, false)
    ACC4_NHWC(p5,  36, c6w, 8, 4, y0, x0, false)
    bool okr0=(unsigned)(gy0-1+y0  )<512u;
    bool okr1=(unsigned)(gy0-1+y0+1)<512u;
    bool okc0=(unsigned)(gx0-1+x0  )<512u;
    bool okc1=(unsigned)(gx0-1+x0+1)<512u;
    PACK_ROWS(rowlo, rowhi, okr0&okc0, okr0&okc1, okr1&okc0, okr1&okc1)
    *(uint4*)&p6[(y0*34+x0)*4]=rowlo;
    *(uint4*)&p6[((y0+1)*34+x0)*4]=rowhi;
  }
  __syncthreads();

  // c7: concat(p1s, p6) -> sigmoid -> v_r, out origin (gy0, gx0)
  if (tid < 256){
    int qy=tid>>4, qx=tid&15, y0=2*qy, x0=2*qx;
    float bv=c7b[0];
    v2f s0=mkv2(bv,bv), s1=s0;
    ACC1_NHWC(p1s, 34, c7w, 0, y0, x0)
    ACC1_NHWC(p6,  34, c7w, 4, y0, x0)
    float* vo = vr + (size_t)b*PLANE;
    *(float2*)&vo[(gy0+y0  )*512 + gx0+x0] =
        make_float2(1.f/(1.f+expf(-s0.x)), 1.f/(1.f+expf(-s0.y)));
    *(float2*)&vo[(gy0+y0+1)*512 + gx0+x0] =
        make_float2(1.f/(1.f+expf(-s1.x)), 1.f/(1.f+expf(-s1.y)));
  }
}

// ---------------- subsample + m-conv(stride2) + leaky + instance norm -> src(S,B,E) ----------------
__launch_bounds__(256)
__global__ void k_mnorm(const float* __restrict__ xg, const float* __restrict__ mw,
                        const float* __restrict__ mb, const float* __restrict__ ing,
                        const float* __restrict__ inb, float* __restrict__ src){
  int bc = blockIdx.x;           // 128 = b*16+c
  int b = bc >> 4, c = bc & 15;
  int tid = threadIdx.x;         // 256 = out pixel (i*16+j)
  int i = tid >> 4, j = tid & 15;
  const float* xp = xg + (size_t)b*3*PLANE;
  float s = mb[c];
  #pragma unroll
  for (int dy=0; dy<3; ++dy){
    int ii = 2*i - 1 + dy;
    if ((unsigned)ii >= 32u) continue;
    #pragma unroll
    for (int dx=0; dx<3; ++dx){
      int jj = 2*j - 1 + dx;
      if ((unsigned)jj >= 32u) continue;
      int off = (ii*16)*W + jj*16;
      float vv = (xp[off] + xp[PLANE+off] + xp[2*PLANE+off]) * (1.f/3.f);
      s += vv * mw[c*9 + dy*3 + dx];
    }
  }
  float h = (s >= 0.f) ? s : 0.2f*s;
  __shared__ float red[256];
  red[tid] = h; __syncthreads();
  for (int off=128; off; off>>=1){ if (tid<off) red[tid]+=red[tid+off]; __syncthreads(); }
  float mu = red[0] * (1.f/256.f);
  __syncthreads();
  float d = h - mu;
  red[tid] = d*d; __syncthreads();
  for (int off=128; off; off>>=1){ if (tid<off) red[tid]+=red[tid+off]; __syncthreads(); }
  float var = red[0] * (1.f/256.f);
  float yv = d * rsqrtf(var + 1e-5f) * ing[c] + inb[c];
  src[(size_t)tid*128 + b*16 + c] = yv;   // src[s][b][e], s=tid
}

// ---------------- qkv projection ----------------
__launch_bounds__(256)
__global__ void k_qkv(const float* __restrict__ src, const float* __restrict__ aw,
                      const float* __restrict__ ab, float* __restrict__ qkv){
  int id = blockIdx.x*256 + threadIdx.x;  // 2048*48 = 98304
  int tok = id / 48, o = id % 48;
  const float* sr = src + tok*16;
  float s = ab[o];
  #pragma unroll
  for (int e=0; e<16; ++e) s += sr[e]*aw[o*16+e];
  qkv[tok*48+o] = s;
}

// ---------------- attention (per b,h block; head dim = 2) ----------------
__launch_bounds__(256)
__global__ void k_attn(const float* __restrict__ qkv, float* __restrict__ obuf){
  int b = blockIdx.x >> 3, hh = blockIdx.x & 7;  // 64 blocks
  int t = threadIdx.x;                           // s index
  __shared__ float kk0[256], kk1[256], vv0[256], vv1[256];
  int tok = t*8 + b;
  const float* qr = qkv + tok*48;
  kk0[t] = qr[16 + hh*2]; kk1[t] = qr[16 + hh*2 + 1];
  vv0[t] = qr[32 + hh*2]; vv1[t] = qr[32 + hh*2 + 1];
  float q0 = qr[hh*2], q1 = qr[hh*2 + 1];
  __syncthreads();
  const float sc = 0.70710678118654752f;  // 1/sqrt(2)
  float m = -1e30f;
  for (int u=0; u<256; ++u){
    float s = (q0*kk0[u] + q1*kk1[u]) * sc;
    m = fmaxf(m, s);
  }
  float l = 0.f, a0 = 0.f, a1 = 0.f;
  for (int u=0; u<256; ++u){
    float s = (q0*kk0[u] + q1*kk1[u]) * sc;
    float p = expf(s - m);
    l += p; a0 += p*vv0[u]; a1 += p*vv1[u];
  }
  float inv = 1.f/l;
  obuf[tok*16 + hh*2]     = a0*inv;
  obuf[tok*16 + hh*2 + 1] = a1*inv;
}

// ---------------- out-proj + residual + layernorm1 (in-place on src) ----------------
__launch_bounds__(256)
__global__ void k_oproj_ln(const float* __restrict__ obuf, const float* __restrict__ ow,
                           const float* __restrict__ obias, const float* __restrict__ g,
                           const float* __restrict__ bb, float* __restrict__ src){
  int tok = blockIdx.x*256 + threadIdx.x;  // 2048
  const float* orow = obuf + tok*16;
  float xv[16];
  #pragma unroll
  for (int e=0; e<16; ++e){
    float s = obias[e];
    #pragma unroll
    for (int f=0; f<16; ++f) s += orow[f]*ow[e*16+f];
    xv[e] = src[tok*16+e] + s;
  }
  float mu = 0.f;
  #pragma unroll
  for (int e=0; e<16; ++e) mu += xv[e];
  mu *= (1.f/16.f);
  float var = 0.f;
  #pragma unroll
  for (int e=0; e<16; ++e){ float d = xv[e]-mu; var += d*d; }
  var *= (1.f/16.f);
  float rs = rsqrtf(var + 1e-5f);
  #pragma unroll
  for (int e=0; e<16; ++e) src[tok*16+e] = (xv[e]-mu)*rs*g[e] + bb[e];
}

// ---------------- FFN + residual + layernorm2 (in-place on src) ----------------
__launch_bounds__(64)
__global__ void k_ffn_ln(float* __restrict__ src, const float* __restrict__ w1,
                         const float* __restrict__ b1, const float* __restrict__ w2,
                         const float* __restrict__ b2, const float* __restrict__ g,
                         const float* __restrict__ bb){
  int tok = blockIdx.x;     // 2048
  int tid = threadIdx.x;    // 64
  __shared__ float srow[16], h1[128], xr[16];
  if (tid < 16) srow[tid] = src[tok*16+tid];
  __syncthreads();
  for (int i = tid; i < 128; i += 64){
    float s = b1[i];
    #pragma unroll
    for (int e=0; e<16; ++e) s += srow[e]*w1[i*16+e];
    h1[i] = fmaxf(s, 0.f);
  }
  __syncthreads();
  if (tid < 16){
    float s = b2[tid];
    for (int j=0; j<128; ++j) s += h1[j]*w2[tid*128+j];
    xr[tid] = srow[tid] + s;
  }
  __syncthreads();
  if (tid < 16){
    float mu = 0.f;
    #pragma unroll
    for (int e=0; e<16; ++e) mu += xr[e];
    mu *= (1.f/16.f);
    float var = 0.f;
    #pragma unroll
    for (int e=0; e<16; ++e){ float d = xr[e]-mu; var += d*d; }
    var *= (1.f/16.f);
    src[tok*16+tid] = (xr[tid]-mu)*rsqrtf(var+1e-5f)*g[tid] + bb[tid];
  }
}

// ---------------- final 16x16 valid conv -> level -> g/bcf scalars ----------------
__launch_bounds__(256)
__global__ void k_level(const float* __restrict__ src, const float* __restrict__ fw,
                        const float* __restrict__ fb, float* __restrict__ gb){
  int b = blockIdx.x >> 1, k = blockIdx.x & 1;  // 16 blocks
  int tid = threadIdx.x;                        // s pixel
  float s = 0.f;
  #pragma unroll
  for (int c=0; c<16; ++c)
    s += src[(size_t)tid*128 + b*16 + c] * fw[(k*16+c)*256 + tid];
  __shared__ float red[256];
  red[tid] = s; __syncthreads();
  for (int off=128; off; off>>=1){ if (tid<off) red[tid]+=red[tid+off]; __syncthreads(); }
  if (tid == 0){
    float lev = 1.f/(1.f + expf(-(red[0] + fb[k])));
    gb[b*2+k] = (k==0) ? (0.1f*lev + 0.2f) : (0.04f*lev + 0.06f);
  }
}

// ---------------- final elementwise: enhance + t ----------------
__launch_bounds__(256)
__global__ void k_final(const float* __restrict__ x, const float* __restrict__ gb,
                        float* __restrict__ out){
  int id = blockIdx.x*256 + threadIdx.x;  // 524288
  int b = id >> 16, p = id & 65535;
  const float4* xr = (const float4*)(x + (size_t)(b*3+0)*PLANE);
  const float4* xg = (const float4*)(x + (size_t)(b*3+1)*PLANE);
  const float4* xb = (const float4*)(x + (size_t)(b*3+2)*PLANE);
  const float4* vrp = (const float4*)(out + 6291456 + (size_t)b*PLANE);
  float4 R = xr[p], G = xg[p], Bl = xb[p], VR = vrp[p];
  float gg = gb[b*2+0], bc = gb[b*2+1];
  float lg = log2f(gg);
  float4 er, eg, eb, tr, tg, tb;
#define COMP(SUF, RF, GF, BF, VRF) {            \
    float vv = (RF + GF + BF)/3.f;              \
    float v0 = fminf(fmaxf(vv, 1e-6f), 0.999999f); \
    float r0 = exp2f(VRF * lg);                 \
    float ev0 = exp2f(r0 * log2f(v0));          \
    float d = bc - vv;                          \
    float L = 400.f*d*d*d;                      \
    L = (L < 1e-5f) ? 1e-6f : L;                \
    float fac = (ev0 - L) / (vv + 1e-6f);       \
    er.SUF = RF*fac; eg.SUF = GF*fac; eb.SUF = BF*fac; \
    bool z = vv > 0.04f;                        \
    tr.SUF = z ? 0.f : er.SUF; tg.SUF = z ? 0.f : eg.SUF; tb.SUF = z ? 0.f : eb.SUF; }
  COMP(x, R.x, G.x, Bl.x, VR.x)
  COMP(y, R.y, G.y, Bl.y, VR.y)
  COMP(z, R.z, G.z, Bl.z, VR.z)
  COMP(w, R.w, G.w, Bl.w, VR.w)
#undef COMP
  float4* oe = (float4*)out;
  float4* ot = (float4*)(out + 8388608);
  oe[(size_t)(b*3+0)*PLANE4 + p] = er;
  oe[(size_t)(b*3+1)*PLANE4 + p] = eg;
  oe[(size_t)(b*3+2)*PLANE4 + p] = eb;
  ot[(size_t)(b*3+0)*PLANE4 + p] = tr;
  ot[(size_t)(b*3+1)*PLANE4 + p] = tg;
  ot[(size_t)(b*3+2)*PLANE4 + p] = tb;
}

extern "C" void kernel_launch(void* const* d_in, const int* in_sizes, int n_in,
                              void* d_out, int out_size, void* d_ws, size_t ws_size,
                              hipStream_t stream) {
  const float* x    = (const float*)d_in[0];
  const float* c1w  = (const float*)d_in[1];  const float* c1b = (const float*)d_in[2];
  const float* c2w  = (const float*)d_in[3];  const float* c2b = (const float*)d_in[4];
  const float* c3w  = (const float*)d_in[5];  const float* c3b = (const float*)d_in[6];
  const float* c4w  = (const float*)d_in[7];  const float* c4b = (const float*)d_in[8];
  const float* c5w  = (const float*)d_in[9];  const float* c5b = (const float*)d_in[10];
  const float* c6w  = (const float*)d_in[11]; const float* c6b = (const float*)d_in[12];
  const float* c7w  = (const float*)d_in[13]; const float* c7b = (const float*)d_in[14];
  const float* mw   = (const float*)d_in[15]; const float* mb  = (const float*)d_in[16];
  const float* ing  = (const float*)d_in[17]; const float* inb = (const float*)d_in[18];
  const float* aw   = (const float*)d_in[19]; const float* ab  = (const float*)d_in[20];
  const float* ow   = (const float*)d_in[21]; const float* ob  = (const float*)d_in[22];
  const float* l1w  = (const float*)d_in[23]; const float* l1b = (const float*)d_in[24];
  const float* l2w  = (const float*)d_in[25]; const float* l2b = (const float*)d_in[26];
  const float* n1g  = (const float*)d_in[27]; const float* n1b = (const float*)d_in[28];
  const float* n2g  = (const float*)d_in[29]; const float* n2b = (const float*)d_in[30];
  const float* fw   = (const float*)d_in[31]; const float* fb  = (const float*)d_in[32];

  ushort* wsu = (ushort*)d_ws;
  ushort* x1p = wsu;                   // each NHWC plane: 8*512*512*4 ushorts = 16.8 MB
  ushort* x2p = x1p + (size_t)8*PLANE*4;
  ushort* x3p = x2p + (size_t)8*PLANE*4;
  ushort* x5p = x3p + (size_t)8*PLANE*4;
  float* smallws = (float*)(x5p + (size_t)8*PLANE*4);
  float* src  = smallws;               // 32,768
  float* qkv  = src + 32768;           // 98,304
  float* obuf = qkv + 98304;           // 32,768
  float* gb   = obuf+ 32768;           // 16
  float* out  = (float*)d_out;
  float* vr   = out + 6291456;         // v_r output region

  k_conv_a<<<2048,512,0,stream>>>(x, c1w,c1b, c2w,c2b, c3w,c3b, x1p, x2p, x3p);
  k_conv_b<<<2048,512,0,stream>>>(x3p, c4w,c4b, c5w,c5b, x5p);
  k_conv_c<<<2048,512,0,stream>>>(x1p, x2p, x5p, c6w,c6b, c7w,c7b, vr);
  k_mnorm<<<128,256,0,stream>>>(x, mw, mb, ing, inb, src);
  k_qkv<<<384,256,0,stream>>>(src, aw, ab, qkv);
  k_attn<<<64,256,0,stream>>>(qkv, obuf);
  k_oproj_ln<<<8,256,0,stream>>>(obuf, ow, ob, n1g, n1b, src);
  k_ffn_ln<<<2048,64,0,stream>>>(src, l1w, l1b, l2w, l2b, n2g, n2b);
  k_level<<<16,256,0,stream>>>(src, fw, fb, gb);
  k_final<<<2048,256,0,stream>>>(x, gb, out);
}

// Round 8
// 255.618 us; speedup vs baseline: 1.7899x; 1.6416x over previous
//
#include <hip/hip_runtime.h>
#include <math.h>

#define H 512
#define W 512
#define PLANE (H*W)       // 262144
#define PLANE4 (PLANE/4)  // 65536

typedef float v2f __attribute__((ext_vector_type(2)));
typedef unsigned int uint;
typedef unsigned short ushort;

// NHWC bf16 plane: idx = ((b*512+y)*512+x)*4 + c
#define PIDX(B,Y,X) (((((size_t)(B)*512)+(Y))*512+(X))*4)

__device__ __forceinline__ float bflo(uint u){ return __uint_as_float(u<<16); }
__device__ __forceinline__ float bfhi(uint u){ return __uint_as_float(u & 0xFFFF0000u); }
__device__ __forceinline__ uint bfpack(float f0, float f1){
  uint a = __float_as_uint(f0), b = __float_as_uint(f1);
  return ((a + 0x8000u) >> 16) | ((b + 0x8000u) & 0xFFFF0000u);
}
__device__ __forceinline__ v2f mkv2(float a, float b){ v2f r; r.x=a; r.y=b; return r; }

// ---- unpack one NHWC row window of 4 pixels (XB even) into P[pixel][ch] ----
#define UNPACK_ROW(P, TL, S, ROWIDX, XB) { \
  uint4 U0 = *(const uint4*)&(TL)[(((ROWIDX))*(S)+(XB))*4]; \
  uint4 U1 = *(const uint4*)&(TL)[(((ROWIDX))*(S)+(XB)+2)*4]; \
  P[0][0]=bflo(U0.x); P[0][1]=bfhi(U0.x); P[0][2]=bflo(U0.y); P[0][3]=bfhi(U0.y); \
  P[1][0]=bflo(U0.z); P[1][1]=bfhi(U0.z); P[1][2]=bflo(U0.w); P[1][3]=bfhi(U0.w); \
  P[2][0]=bflo(U1.x); P[2][1]=bfhi(U1.x); P[2][2]=bflo(U1.y); P[2][3]=bfhi(U1.y); \
  P[3][0]=bflo(U1.z); P[3][1]=bfhi(U1.z); P[3][2]=bflo(U1.w); P[3][3]=bfhi(U1.w); }

// XB odd: pixels XB..XB+3 via three aligned uint4 (XB-1 even)
#define UNPACK_ROW_ODD(P, TL, S, ROWIDX, XB) { \
  uint4 U0 = *(const uint4*)&(TL)[(((ROWIDX))*(S)+(XB)-1)*4]; \
  uint4 U1 = *(const uint4*)&(TL)[(((ROWIDX))*(S)+(XB)+1)*4]; \
  uint4 U2 = *(const uint4*)&(TL)[(((ROWIDX))*(S)+(XB)+3)*4]; \
  P[0][0]=bflo(U0.z); P[0][1]=bfhi(U0.z); P[0][2]=bflo(U0.w); P[0][3]=bfhi(U0.w); \
  P[1][0]=bflo(U1.x); P[1][1]=bfhi(U1.x); P[1][2]=bflo(U1.y); P[1][3]=bfhi(U1.y); \
  P[2][0]=bflo(U1.z); P[2][1]=bfhi(U1.z); P[2][2]=bflo(U1.w); P[2][3]=bfhi(U1.w); \
  P[3][0]=bflo(U2.x); P[3][1]=bfhi(U2.x); P[3][2]=bflo(U2.y); P[3][3]=bfhi(U2.y); }

// one dy slice, 4 ci x 4 co, packed pairs. RL=top rows, RH=bottom rows.
#define DY4(RL, RH, Wb, INC, CIB, DYI) { \
  _Pragma("unroll") \
  for (int ci=0;ci<4;++ci){ \
    v2f A0=mkv2(RL[0][ci],RL[1][ci]), M0=mkv2(RL[1][ci],RL[2][ci]), B0=mkv2(RL[2][ci],RL[3][ci]); \
    v2f A1=mkv2(RH[0][ci],RH[1][ci]), M1=mkv2(RH[1][ci],RH[2][ci]), B1=mkv2(RH[2][ci],RH[3][ci]); \
    _Pragma("unroll") \
    for (int co=0;co<4;++co){ \
      const float* wp = (Wb) + ((co*(INC))+(CIB)+ci)*9 + (DYI)*3; \
      float w0=wp[0], w1=wp[1], w2=wp[2]; \
      acc0[co]+=A0*w0; acc0[co]+=M0*w1; acc0[co]+=B0*w2; \
      acc1[co]+=A1*w0; acc1[co]+=M1*w1; acc1[co]+=B1*w2; \
    } } }

#define ACC4_NHWC(TL, S, Wb, INC, CIB, YB, XB, ODDF) { \
  float r0_[4][4], r1_[4][4], r2_[4][4], r3_[4][4]; \
  if (ODDF){ UNPACK_ROW_ODD(r0_,TL,S,(YB)+0,XB) UNPACK_ROW_ODD(r1_,TL,S,(YB)+1,XB) } \
  else     { UNPACK_ROW(r0_,TL,S,(YB)+0,XB)     UNPACK_ROW(r1_,TL,S,(YB)+1,XB) } \
  DY4(r0_, r1_, Wb, INC, CIB, 0) \
  if (ODDF){ UNPACK_ROW_ODD(r2_,TL,S,(YB)+2,XB) } else { UNPACK_ROW(r2_,TL,S,(YB)+2,XB) } \
  DY4(r1_, r2_, Wb, INC, CIB, 1) \
  if (ODDF){ UNPACK_ROW_ODD(r3_,TL,S,(YB)+3,XB) } else { UNPACK_ROW(r3_,TL,S,(YB)+3,XB) } \
  DY4(r2_, r3_, Wb, INC, CIB, 2) }

// single-output-channel (c7)
#define DY1(RL, RH, Wb, CIB, DYI) { \
  _Pragma("unroll") \
  for (int ci=0;ci<4;++ci){ \
    v2f A0=mkv2(RL[0][ci],RL[1][ci]), M0=mkv2(RL[1][ci],RL[2][ci]), B0=mkv2(RL[2][ci],RL[3][ci]); \
    v2f A1=mkv2(RH[0][ci],RH[1][ci]), M1=mkv2(RH[1][ci],RH[2][ci]), B1=mkv2(RH[2][ci],RH[3][ci]); \
    const float* wp=(Wb)+((CIB)+ci)*9+(DYI)*3; \
    float w0=wp[0],w1=wp[1],w2=wp[2]; \
    s0+=A0*w0; s0+=M0*w1; s0+=B0*w2; \
    s1+=A1*w0; s1+=M1*w1; s1+=B1*w2; } }

#define ACC1_NHWC(TL, S, Wb, CIB, YB, XB) { \
  float r0_[4][4], r1_[4][4], r2_[4][4], r3_[4][4]; \
  UNPACK_ROW(r0_,TL,S,(YB)+0,XB) UNPACK_ROW(r1_,TL,S,(YB)+1,XB) \
  DY1(r0_,r1_,Wb,CIB,0) \
  UNPACK_ROW(r2_,TL,S,(YB)+2,XB) \
  DY1(r1_,r2_,Wb,CIB,1) \
  UNPACK_ROW(r3_,TL,S,(YB)+3,XB) \
  DY1(r2_,r3_,Wb,CIB,2) }

// scalar-plane (v) -> 4 co (c1); XB even, stride S ushorts
template<int S>
__device__ __forceinline__ void accp4sc(const ushort* __restrict__ pl,
    const float* __restrict__ w, int YB, int XB, v2f* acc0, v2f* acc1)
{
  v2f A[4], Mv[4], Bv[4];
  #pragma unroll
  for (int r=0;r<4;++r){
    const ushort* rp = pl + (YB+r)*S + XB;
    uint u0 = *(const uint*)rp;
    uint u1 = *(const uint*)(rp+2);
    float q0=bflo(u0), q1=bfhi(u0), q2=bflo(u1), q3=bfhi(u1);
    A[r]=mkv2(q0,q1); Mv[r]=mkv2(q1,q2); Bv[r]=mkv2(q2,q3);
  }
  #pragma unroll
  for (int dy=0; dy<3; ++dy){
    #pragma unroll
    for (int co=0; co<4; ++co){
      float w0=w[co*9+dy*3+0], w1=w[co*9+dy*3+1], w2=w[co*9+dy*3+2];
      acc0[co] += A[dy]*w0;   acc0[co] += Mv[dy]*w1;   acc0[co] += Bv[dy]*w2;
      acc1[co] += A[dy+1]*w0; acc1[co] += Mv[dy+1]*w1; acc1[co] += Bv[dy+1]*w2;
    }
  }
}

// pack quad accumulators (masked relu) into two NHWC row uint4s
#define PACK_ROWS(RL4, RH4, M00, M01, M10, M11) \
  uint4 RL4, RH4; { \
    float v00[4],v01[4],v10[4],v11[4]; \
    _Pragma("unroll") \
    for (int co=0;co<4;++co){ \
      v00[co]=(M00)?fmaxf(acc0[co].x,0.f):0.f; \
      v01[co]=(M01)?fmaxf(acc0[co].y,0.f):0.f; \
      v10[co]=(M10)?fmaxf(acc1[co].x,0.f):0.f; \
      v11[co]=(M11)?fmaxf(acc1[co].y,0.f):0.f; } \
    RL4.x=bfpack(v00[0],v00[1]); RL4.y=bfpack(v00[2],v00[3]); \
    RL4.z=bfpack(v01[0],v01[1]); RL4.w=bfpack(v01[2],v01[3]); \
    RH4.x=bfpack(v10[0],v10[1]); RH4.y=bfpack(v10[2],v10[3]); \
    RH4.z=bfpack(v11[0],v11[1]); RH4.w=bfpack(v11[2],v11[3]); }

// ================= K1: v -> x1 -> x2 -> x3 (bf16 NHWC) =================
__launch_bounds__(512,2)
__global__ void k_conv_a(const float* __restrict__ xg,
    const float* __restrict__ c1w, const float* __restrict__ c1b,
    const float* __restrict__ c2w, const float* __restrict__ c2b,
    const float* __restrict__ c3w, const float* __restrict__ c3b,
    ushort* __restrict__ x1p, ushort* __restrict__ x2p, ushort* __restrict__ x3p)
{
  __shared__ __align__(16) ushort vb[38*38];
  __shared__ __align__(16) ushort p1[36*36*4];
  __shared__ __align__(16) ushort p2[34*34*4];
  int wg=blockIdx.x, b=wg>>8, t=wg&255, ty=t>>4, tx=t&15;
  int gy0=ty*32, gx0=tx*32, tid=threadIdx.x;
  const float* xp = xg + (size_t)b*3*PLANE;

  for (int i=tid;i<38*38;i+=512){
    int rr=i/38, cc=i-rr*38;
    int gy=gy0-3+rr, gx=gx0-3+cc;
    float val=0.f;
    if (((unsigned)gy<512u)&((unsigned)gx<512u)){
      int off=gy*W+gx;
      val=(xp[off]+xp[PLANE+off]+xp[2*PLANE+off])*(1.f/3.f);
    }
    vb[i]=(ushort)((__float_as_uint(val)+0x8000u)>>16);
  }
  __syncthreads();

  // c1: vb(38) -> p1(36 NHWC) + x1 global, out origin (gy0-2, gx0-2)
  if (tid < 324){
    int qy=tid/18, qx=tid-qy*18, y0=2*qy, x0=2*qx;
    v2f acc0[4], acc1[4];
    #pragma unroll
    for (int co=0;co<4;++co){ float bv=c1b[co]; acc0[co]=mkv2(bv,bv); acc1[co]=acc0[co]; }
    accp4sc<38>(vb, c1w, y0, x0, acc0, acc1);
    bool okr0=(unsigned)(gy0-2+y0  )<512u;
    bool okr1=(unsigned)(gy0-2+y0+1)<512u;
    bool okc0=(unsigned)(gx0-2+x0  )<512u;
    bool okc1=(unsigned)(gx0-2+x0+1)<512u;
    PACK_ROWS(rowlo, rowhi, okr0&okc0, okr0&okc1, okr1&okc0, okr1&okc1)
    *(uint4*)&p1[(y0*36+x0)*4]=rowlo;
    *(uint4*)&p1[((y0+1)*36+x0)*4]=rowhi;
    if ((x0>=2)&(x0<33)){
      if ((y0>=2)&(y0<34))   *(uint4*)&x1p[PIDX(b, gy0-2+y0,   gx0-2+x0)]=rowlo;
      if ((y0+1>=2)&(y0+1<34)) *(uint4*)&x1p[PIDX(b, gy0-2+y0+1, gx0-2+x0)]=rowhi;
    }
  }
  __syncthreads();

  // c2: p1(36) -> p2(34) + x2 global, out origin (gy0-1, gx0-1)
  if (tid < 289){
    int qy=tid/17, qx=tid-qy*17, y0=2*qy, x0=2*qx;
    v2f acc0[4], acc1[4];
    #pragma unroll
    for (int co=0;co<4;++co){ float bv=c2b[co]; acc0[co]=mkv2(bv,bv); acc1[co]=acc0[co]; }
    ACC4_NHWC(p1, 36, c2w, 4, 0, y0, x0, false)
    bool okr0=(unsigned)(gy0-1+y0  )<512u;
    bool okr1=(unsigned)(gy0-1+y0+1)<512u;
    bool okc0=(unsigned)(gx0-1+x0  )<512u;
    bool okc1=(unsigned)(gx0-1+x0+1)<512u;
    PACK_ROWS(rowlo, rowhi, okr0&okc0, okr0&okc1, okr1&okc0, okr1&okc1)
    *(uint4*)&p2[(y0*34+x0)*4]=rowlo;
    *(uint4*)&p2[((y0+1)*34+x0)*4]=rowhi;
    bool own0=(unsigned)(y0-1)<32u;
    bool own1=(unsigned)(y0)<32u;
    int gyA=gy0-1+y0, gxA=gx0-1+x0;
    uint2 px00=make_uint2(rowlo.x,rowlo.y), px01=make_uint2(rowlo.z,rowlo.w);
    uint2 px10=make_uint2(rowhi.x,rowhi.y), px11=make_uint2(rowhi.z,rowhi.w);
    if (x0==0){
      if (own0) *(uint2*)&x2p[PIDX(b,gyA,  gxA+1)]=px01;
      if (own1) *(uint2*)&x2p[PIDX(b,gyA+1,gxA+1)]=px11;
    } else if (x0==32){
      if (own0) *(uint2*)&x2p[PIDX(b,gyA,  gxA)]=px00;
      if (own1) *(uint2*)&x2p[PIDX(b,gyA+1,gxA)]=px10;
    } else {
      if (own0){ *(uint2*)&x2p[PIDX(b,gyA,  gxA)]=px00; *(uint2*)&x2p[PIDX(b,gyA,  gxA+1)]=px01; }
      if (own1){ *(uint2*)&x2p[PIDX(b,gyA+1,gxA)]=px10; *(uint2*)&x2p[PIDX(b,gyA+1,gxA+1)]=px11; }
    }
  }
  __syncthreads();

  // c3: p2(34) -> x3 global, out origin (gy0, gx0), interior
  if (tid < 256){
    int qy=tid>>4, qx=tid&15, y0=2*qy, x0=2*qx;
    v2f acc0[4], acc1[4];
    #pragma unroll
    for (int co=0;co<4;++co){ float bv=c3b[co]; acc0[co]=mkv2(bv,bv); acc1[co]=acc0[co]; }
    ACC4_NHWC(p2, 34, c3w, 4, 0, y0, x0, false)
    PACK_ROWS(rowlo, rowhi, true, true, true, true)
    *(uint4*)&x3p[PIDX(b, gy0+y0,   gx0+x0)]=rowlo;
    *(uint4*)&x3p[PIDX(b, gy0+y0+1, gx0+x0)]=rowhi;
  }
}

// ================= K2: x3 -> x4 -> x5 (bf16 NHWC) =================
__launch_bounds__(512,2)
__global__ void k_conv_b(const ushort* __restrict__ x3p,
    const float* __restrict__ c4w, const float* __restrict__ c4b,
    const float* __restrict__ c5w, const float* __restrict__ c5b,
    ushort* __restrict__ x5p)
{
  __shared__ __align__(16) ushort p3[36*36*4];
  __shared__ __align__(16) ushort p4[34*34*4];
  int wg=blockIdx.x, b=wg>>8, t=wg&255, ty=t>>4, tx=t&15;
  int gy0=ty*32, gx0=tx*32, tid=threadIdx.x;

  // stage x3 window (origin gy0-2, gx0-2): 36 rows x 18 uint4 (2 px each)
  for (int i=tid; i<648; i+=512){
    int rr=i/18, cu=i-rr*18;
    int gy=gy0-2+rr, gx=gx0-2+2*cu;
    uint4 u=make_uint4(0,0,0,0);
    if (((unsigned)gy<512u)&((unsigned)gx<=510u))
      u = *(const uint4*)&x3p[PIDX(b,gy,gx)];
    *(uint4*)&p3[(rr*36+2*cu)*4]=u;
  }
  __syncthreads();

  // c4: p3(36) -> p4(34), out origin (gy0-1, gx0-1)
  if (tid < 289){
    int qy=tid/17, qx=tid-qy*17, y0=2*qy, x0=2*qx;
    v2f acc0[4], acc1[4];
    #pragma unroll
    for (int co=0;co<4;++co){ float bv=c4b[co]; acc0[co]=mkv2(bv,bv); acc1[co]=acc0[co]; }
    ACC4_NHWC(p3, 36, c4w, 4, 0, y0, x0, false)
    bool okr0=(unsigned)(gy0-1+y0  )<512u;
    bool okr1=(unsigned)(gy0-1+y0+1)<512u;
    bool okc0=(unsigned)(gx0-1+x0  )<512u;
    bool okc1=(unsigned)(gx0-1+x0+1)<512u;
    PACK_ROWS(rowlo, rowhi, okr0&okc0, okr0&okc1, okr1&okc0, okr1&okc1)
    *(uint4*)&p4[(y0*34+x0)*4]=rowlo;
    *(uint4*)&p4[((y0+1)*34+x0)*4]=rowhi;
  }
  __syncthreads();

  // c5: concat(p3 shifted (+1,+1) [odd], p4) -> x5, out origin (gy0, gx0)
  if (tid < 256){
    int qy=tid>>4, qx=tid&15, y0=2*qy, x0=2*qx;
    v2f acc0[4], acc1[4];
    #pragma unroll
    for (int co=0;co<4;++co){ float bv=c5b[co]; acc0[co]=mkv2(bv,bv); acc1[co]=acc0[co]; }
    ACC4_NHWC(p3, 36, c5w, 8, 0, y0+1, x0+1, true)
    ACC4_NHWC(p4, 34, c5w, 8, 4, y0,   x0,   false)
    PACK_ROWS(rowlo, rowhi, true, true, true, true)
    *(uint4*)&x5p[PIDX(b, gy0+y0,   gx0+x0)]=rowlo;
    *(uint4*)&x5p[PIDX(b, gy0+y0+1, gx0+x0)]=rowhi;
  }
}

// ================= K3: x2,x5 -> x6 ; x1,x6 -> v_r =================
__launch_bounds__(512,2)
__global__ void k_conv_c(const ushort* __restrict__ x1p,
    const ushort* __restrict__ x2p, const ushort* __restrict__ x5p,
    const float* __restrict__ c6w, const float* __restrict__ c6b,
    const float* __restrict__ c7w, const float* __restrict__ c7b,
    float* __restrict__ vr)
{
  __shared__ __align__(16) ushort p2s[36*36*4];
  __shared__ __align__(16) ushort p5 [36*36*4];
  __shared__ __align__(16) ushort p1s[34*34*4];
  __shared__ __align__(16) ushort p6 [34*34*4];
  int wg=blockIdx.x, b=wg>>8, t=wg&255, ty=t>>4, tx=t&15;
  int gy0=ty*32, gx0=tx*32, tid=threadIdx.x;

  // stage x2 and x5 windows (origin gy0-2, gx0-2): 2 x 36 rows x 18 uint4
  for (int i=tid; i<1296; i+=512){
    int pi=i/648; int rem=i-pi*648;
    int rr=rem/18, cu=rem-rr*18;
    int gy=gy0-2+rr, gx=gx0-2+2*cu;
    uint4 u=make_uint4(0,0,0,0);
    const ushort* sp = pi==0 ? x2p : x5p;
    if (((unsigned)gy<512u)&((unsigned)gx<=510u))
      u = *(const uint4*)&sp[PIDX(b,gy,gx)];
    if (pi==0) *(uint4*)&p2s[(rr*36+2*cu)*4]=u;
    else       *(uint4*)&p5 [(rr*36+2*cu)*4]=u;
  }
  // stage x1 window (origin gy0-1, gx0-1): 34 rows x 34 px, uint2 each
  for (int i=tid; i<1156; i+=512){
    int rr=i/34, px=i-rr*34;
    int gy=gy0-1+rr, gx=gx0-1+px;
    uint2 u=make_uint2(0,0);
    if (((unsigned)gy<512u)&((unsigned)gx<512u))
      u = *(const uint2*)&x1p[PIDX(b,gy,gx)];
    *(uint2*)&p1s[(rr*34+px)*4]=u;
  }
  __syncthreads();

  // c6: concat(p2s, p5) -> p6(34), out origin (gy0-1, gx0-1)
  if (tid < 289){
    int qy=tid/17, qx=tid-qy*17, y0=2*qy, x0=2*qx;
    v2f acc0[4], acc1[4];
    #pragma unroll
    for (int co=0;co<4;++co){ float bv=c6b[co]; acc0[co]=mkv2(bv,bv); acc1[co]=acc0[co]; }
    ACC4_NHWC(p2s, 36, c6w, 8, 0, y0, x0, false)
    ACC4_NHWC(p5,  36, c6w, 8, 4, y0, x0, false)
    bool okr0=(unsigned)(gy0-1+y0  )<512u;
    bool okr1=(unsigned)(gy0-1+y0+1)<512u;
    bool okc0=(unsigned)(gx0-1+x0  )<512u;
    bool okc1=(unsigned)(gx0-1+x0+1)<512u;
    PACK_ROWS(rowlo, rowhi, okr0&okc0, okr0&okc1, okr1&okc0, okr1&okc1)
    *(uint4*)&p6[(y0*34+x0)*4]=rowlo;
    *(uint4*)&p6[((y0+1)*34+x0)*4]=rowhi;
  }
  __syncthreads();

  // c7: concat(p1s, p6) -> sigmoid -> v_r, out origin (gy0, gx0)
  if (tid < 256){
    int qy=tid>>4, qx=tid&15, y0=2*qy, x0=2*qx;
    float bv=c7b[0];
    v2f s0=mkv2(bv,bv), s1=s0;
    ACC1_NHWC(p1s, 34, c7w, 0, y0, x0)
    ACC1_NHWC(p6,  34, c7w, 4, y0, x0)
    float* vo = vr + (size_t)b*PLANE;
    *(float2*)&vo[(gy0+y0  )*512 + gx0+x0] =
        make_float2(1.f/(1.f+expf(-s0.x)), 1.f/(1.f+expf(-s0.y)));
    *(float2*)&vo[(gy0+y0+1)*512 + gx0+x0] =
        make_float2(1.f/(1.f+expf(-s1.x)), 1.f/(1.f+expf(-s1.y)));
  }
}

// ---------------- subsample + m-conv(stride2) + leaky + instance norm -> src(S,B,E) ----------------
__launch_bounds__(256)
__global__ void k_mnorm(const float* __restrict__ xg, const float* __restrict__ mw,
                        const float* __restrict__ mb, const float* __restrict__ ing,
                        const float* __restrict__ inb, float* __restrict__ src){
  int bc = blockIdx.x;           // 128 = b*16+c
  int b = bc >> 4, c = bc & 15;
  int tid = threadIdx.x;         // 256 = out pixel (i*16+j)
  int i = tid >> 4, j = tid & 15;
  const float* xp = xg + (size_t)b*3*PLANE;
  float s = mb[c];
  #pragma unroll
  for (int dy=0; dy<3; ++dy){
    int ii = 2*i - 1 + dy;
    if ((unsigned)ii >= 32u) continue;
    #pragma unroll
    for (int dx=0; dx<3; ++dx){
      int jj = 2*j - 1 + dx;
      if ((unsigned)jj >= 32u) continue;
      int off = (ii*16)*W + jj*16;
      float vv = (xp[off] + xp[PLANE+off] + xp[2*PLANE+off]) * (1.f/3.f);
      s += vv * mw[c*9 + dy*3 + dx];
    }
  }
  float h = (s >= 0.f) ? s : 0.2f*s;
  __shared__ float red[256];
  red[tid] = h; __syncthreads();
  for (int off=128; off; off>>=1){ if (tid<off) red[tid]+=red[tid+off]; __syncthreads(); }
  float mu = red[0] * (1.f/256.f);
  __syncthreads();
  float d = h - mu;
  red[tid] = d*d; __syncthreads();
  for (int off=128; off; off>>=1){ if (tid<off) red[tid]+=red[tid+off]; __syncthreads(); }
  float var = red[0] * (1.f/256.f);
  float yv = d * rsqrtf(var + 1e-5f) * ing[c] + inb[c];
  src[(size_t)tid*128 + b*16 + c] = yv;   // src[s][b][e], s=tid
}

// ---------------- qkv projection ----------------
__launch_bounds__(256)
__global__ void k_qkv(const float* __restrict__ src, const float* __restrict__ aw,
                      const float* __restrict__ ab, float* __restrict__ qkv){
  int id = blockIdx.x*256 + threadIdx.x;  // 2048*48 = 98304
  int tok = id / 48, o = id % 48;
  const float* sr = src + tok*16;
  float s = ab[o];
  #pragma unroll
  for (int e=0; e<16; ++e) s += sr[e]*aw[o*16+e];
  qkv[tok*48+o] = s;
}

// ---------------- attention (per b,h block; head dim = 2) ----------------
__launch_bounds__(256)
__global__ void k_attn(const float* __restrict__ qkv, float* __restrict__ obuf){
  int b = blockIdx.x >> 3, hh = blockIdx.x & 7;  // 64 blocks
  int t = threadIdx.x;                           // s index
  __shared__ float kk0[256], kk1[256], vv0[256], vv1[256];
  int tok = t*8 + b;
  const float* qr = qkv + tok*48;
  kk0[t] = qr[16 + hh*2]; kk1[t] = qr[16 + hh*2 + 1];
  vv0[t] = qr[32 + hh*2]; vv1[t] = qr[32 + hh*2 + 1];
  float q0 = qr[hh*2], q1 = qr[hh*2 + 1];
  __syncthreads();
  const float sc = 0.70710678118654752f;  // 1/sqrt(2)
  float m = -1e30f;
  for (int u=0; u<256; ++u){
    float s = (q0*kk0[u] + q1*kk1[u]) * sc;
    m = fmaxf(m, s);
  }
  float l = 0.f, a0 = 0.f, a1 = 0.f;
  for (int u=0; u<256; ++u){
    float s = (q0*kk0[u] + q1*kk1[u]) * sc;
    float p = expf(s - m);
    l += p; a0 += p*vv0[u]; a1 += p*vv1[u];
  }
  float inv = 1.f/l;
  obuf[tok*16 + hh*2]     = a0*inv;
  obuf[tok*16 + hh*2 + 1] = a1*inv;
}

// ---------------- out-proj + residual + layernorm1 (in-place on src) ----------------
__launch_bounds__(256)
__global__ void k_oproj_ln(const float* __restrict__ obuf, const float* __restrict__ ow,
                           const float* __restrict__ obias, const float* __restrict__ g,
                           const float* __restrict__ bb, float* __restrict__ src){
  int tok = blockIdx.x*256 + threadIdx.x;  // 2048
  const float* orow = obuf + tok*16;
  float xv[16];
  #pragma unroll
  for (int e=0; e<16; ++e){
    float s = obias[e];
    #pragma unroll
    for (int f=0; f<16; ++f) s += orow[f]*ow[e*16+f];
    xv[e] = src[tok*16+e] + s;
  }
  float mu = 0.f;
  #pragma unroll
  for (int e=0; e<16; ++e) mu += xv[e];
  mu *= (1.f/16.f);
  float var = 0.f;
  #pragma unroll
  for (int e=0; e<16; ++e){ float d = xv[e]-mu; var += d*d; }
  var *= (1.f/16.f);
  float rs = rsqrtf(var + 1e-5f);
  #pragma unroll
  for (int e=0; e<16; ++e) src[tok*16+e] = (xv[e]-mu)*rs*g[e] + bb[e];
}

// ---------------- FFN + residual + layernorm2 (in-place on src) ----------------
__launch_bounds__(64)
__global__ void k_ffn_ln(float* __restrict__ src, const float* __restrict__ w1,
                         const float* __restrict__ b1, const float* __restrict__ w2,
                         const float* __restrict__ b2, const float* __restrict__ g,
                         const float* __restrict__ bb){
  int tok = blockIdx.x;     // 2048
  int tid = threadIdx.x;    // 64
  __shared__ float srow[16], h1[128], xr[16];
  if (tid < 16) srow[tid] = src[tok*16+tid];
  __syncthreads();
  for (int i = tid; i < 128; i += 64){
    float s = b1[i];
    #pragma unroll
    for (int e=0; e<16; ++e) s += srow[e]*w1[i*16+e];
    h1[i] = fmaxf(s, 0.f);
  }
  __syncthreads();
  if (tid < 16){
    float s = b2[tid];
    for (int j=0; j<128; ++j) s += h1[j]*w2[tid*128+j];
    xr[tid] = srow[tid] + s;
  }
  __syncthreads();
  if (tid < 16){
    float mu = 0.f;
    #pragma unroll
    for (int e=0; e<16; ++e) mu += xr[e];
    mu *= (1.f/16.f);
    float var = 0.f;
    #pragma unroll
    for (int e=0; e<16; ++e){ float d = xr[e]-mu; var += d*d; }
    var *= (1.f/16.f);
    src[tok*16+tid] = (xr[tid]-mu)*rsqrtf(var+1e-5f)*g[tid] + bb[tid];
  }
}

// ---------------- final 16x16 valid conv -> level -> g/bcf scalars ----------------
__launch_bounds__(256)
__global__ void k_level(const float* __restrict__ src, const float* __restrict__ fw,
                        const float* __restrict__ fb, float* __restrict__ gb){
  int b = blockIdx.x >> 1, k = blockIdx.x & 1;  // 16 blocks
  int tid = threadIdx.x;                        // s pixel
  float s = 0.f;
  #pragma unroll
  for (int c=0; c<16; ++c)
    s += src[(size_t)tid*128 + b*16 + c] * fw[(k*16+c)*256 + tid];
  __shared__ float red[256];
  red[tid] = s; __syncthreads();
  for (int off=128; off; off>>=1){ if (tid<off) red[tid]+=red[tid+off]; __syncthreads(); }
  if (tid == 0){
    float lev = 1.f/(1.f + expf(-(red[0] + fb[k])));
    gb[b*2+k] = (k==0) ? (0.1f*lev + 0.2f) : (0.04f*lev + 0.06f);
  }
}

// ---------------- final elementwise: enhance + t ----------------
__launch_bounds__(256)
__global__ void k_final(const float* __restrict__ x, const float* __restrict__ gb,
                        float* __restrict__ out){
  int id = blockIdx.x*256 + threadIdx.x;  // 524288
  int b = id >> 16, p = id & 65535;
  const float4* xr = (const float4*)(x + (size_t)(b*3+0)*PLANE);
  const float4* xg = (const float4*)(x + (size_t)(b*3+1)*PLANE);
  const float4* xb = (const float4*)(x + (size_t)(b*3+2)*PLANE);
  const float4* vrp = (const float4*)(out + 6291456 + (size_t)b*PLANE);
  float4 R = xr[p], G = xg[p], Bl = xb[p], VR = vrp[p];
  float gg = gb[b*2+0], bc = gb[b*2+1];
  float lg = log2f(gg);
  float4 er, eg, eb, tr, tg, tb;
#define COMP(SUF, RF, GF, BF, VRF) {            \
    float vv = (RF + GF + BF)/3.f;              \
    float v0 = fminf(fmaxf(vv, 1e-6f), 0.999999f); \
    float r0 = exp2f(VRF * lg);                 \
    float ev0 = exp2f(r0 * log2f(v0));          \
    float d = bc - vv;                          \
    float L = 400.f*d*d*d;                      \
    L = (L < 1e-5f) ? 1e-6f : L;                \
    float fac = (ev0 - L) / (vv + 1e-6f);       \
    er.SUF = RF*fac; eg.SUF = GF*fac; eb.SUF = BF*fac; \
    bool z = vv > 0.04f;                        \
    tr.SUF = z ? 0.f : er.SUF; tg.SUF = z ? 0.f : eg.SUF; tb.SUF = z ? 0.f : eb.SUF; }
  COMP(x, R.x, G.x, Bl.x, VR.x)
  COMP(y, R.y, G.y, Bl.y, VR.y)
  COMP(z, R.z, G.z, Bl.z, VR.z)
  COMP(w, R.w, G.w, Bl.w, VR.w)
#undef COMP
  float4* oe = (float4*)out;
  float4* ot = (float4*)(out + 8388608);
  oe[(size_t)(b*3+0)*PLANE4 + p] = er;
  oe[(size_t)(b*3+1)*PLANE4 + p] = eg;
  oe[(size_t)(b*3+2)*PLANE4 + p] = eb;
  ot[(size_t)(b*3+0)*PLANE4 + p] = tr;
  ot[(size_t)(b*3+1)*PLANE4 + p] = tg;
  ot[(size_t)(b*3+2)*PLANE4 + p] = tb;
}

extern "C" void kernel_launch(void* const* d_in, const int* in_sizes, int n_in,
                              void* d_out, int out_size, void* d_ws, size_t ws_size,
                              hipStream_t stream) {
  const float* x    = (const float*)d_in[0];
  const float* c1w  = (const float*)d_in[1];  const float* c1b = (const float*)d_in[2];
  const float* c2w  = (const float*)d_in[3];  const float* c2b = (const float*)d_in[4];
  const float* c3w  = (const float*)d_in[5];  const float* c3b = (const float*)d_in[6];
  const float* c4w  = (const float*)d_in[7];  const float* c4b = (const float*)d_in[8];
  const float* c5w  = (const float*)d_in[9];  const float* c5b = (const float*)d_in[10];
  const float* c6w  = (const float*)d_in[11]; const float* c6b = (const float*)d_in[12];
  const float* c7w  = (const float*)d_in[13]; const float* c7b = (const float*)d_in[14];
  const float* mw   = (const float*)d_in[15]; const float* mb  = (const float*)d_in[16];
  const float* ing  = (const float*)d_in[17]; const float* inb = (const float*)d_in[18];
  const float* aw   = (const float*)d_in[19]; const float* ab  = (const float*)d_in[20];
  const float* ow   = (const float*)d_in[21]; const float* ob  = (const float*)d_in[22];
  const float* l1w  = (const float*)d_in[23]; const float* l1b = (const float*)d_in[24];
  const float* l2w  = (const float*)d_in[25]; const float* l2b = (const float*)d_in[26];
  const float* n1g  = (const float*)d_in[27]; const float* n1b = (const float*)d_in[28];
  const float* n2g  = (const float*)d_in[29]; const float* n2b = (const float*)d_in[30];
  const float* fw   = (const float*)d_in[31]; const float* fb  = (const float*)d_in[32];

  ushort* wsu = (ushort*)d_ws;
  ushort* x1p = wsu;                   // each NHWC plane: 8*512*512*4 ushorts = 16.8 MB
  ushort* x2p = x1p + (size_t)8*PLANE*4;
  ushort* x3p = x2p + (size_t)8*PLANE*4;
  ushort* x5p = x3p + (size_t)8*PLANE*4;
  float* smallws = (float*)(x5p + (size_t)8*PLANE*4);
  float* src  = smallws;               // 32,768
  float* qkv  = src + 32768;           // 98,304
  float* obuf = qkv + 98304;           // 32,768
  float* gb   = obuf+ 32768;           // 16
  float* out  = (float*)d_out;
  float* vr   = out + 6291456;         // v_r output region

  k_conv_a<<<2048,512,0,stream>>>(x, c1w,c1b, c2w,c2b, c3w,c3b, x1p, x2p, x3p);
  k_conv_b<<<2048,512,0,stream>>>(x3p, c4w,c4b, c5w,c5b, x5p);
  k_conv_c<<<2048,512,0,stream>>>(x1p, x2p, x5p, c6w,c6b, c7w,c7b, vr);
  k_mnorm<<<128,256,0,stream>>>(x, mw, mb, ing, inb, src);
  k_qkv<<<384,256,0,stream>>>(src, aw, ab, qkv);
  k_attn<<<64,256,0,stream>>>(qkv, obuf);
  k_oproj_ln<<<8,256,0,stream>>>(obuf, ow, ob, n1g, n1b, src);
  k_ffn_ln<<<2048,64,0,stream>>>(src, l1w, l1b, l2w, l2b, n2g, n2b);
  k_level<<<16,256,0,stream>>>(src, fw, fb, gb);
  k_final<<<2048,256,0,stream>>>(x, gb, out);
}